// Round 12
// baseline (3395.708 us; speedup 1.0000x reference)
//
#include <hip/hip_runtime.h>
#include <hip/hip_bf16.h>

typedef _Float16 f16;
typedef __attribute__((ext_vector_type(8))) _Float16 f16x8;
typedef __attribute__((ext_vector_type(4))) _Float16 f16x4;
typedef __attribute__((ext_vector_type(4))) float f32x4;

#define GLOAD_LDS16(gp, lp) \
  __builtin_amdgcn_global_load_lds((const __attribute__((address_space(1))) void*)(gp), \
                                   (__attribute__((address_space(3))) void*)(lp), 16, 0, 0)

// ---------------- all weight casts in one dispatch; wqk/wv stacked into Wqv ----------------
__global__ __launch_bounds__(256) void cast_all_k(const float* __restrict__ cw,
                                                  const float* __restrict__ wqk,
                                                  const float* __restrict__ wv,
                                                  const float* __restrict__ wt,
                                                  f16* __restrict__ Wc, f16* __restrict__ Wqv,
                                                  f16* __restrict__ Wt_){
  int y = blockIdx.y;
  int i = (blockIdx.x * 256 + threadIdx.x) * 4;
  const float* in; f16* out; int n; long oidx;
  if (y == 0){ in = cw;  n = 6 * 65536; out = Wc;  oidx = i; }
  else if (y == 1){ in = wqk; n = 8 * 65536; out = Wqv; oidx = (long)(i >> 16) * 131072 + (i & 65535); }
  else if (y == 2){ in = wv;  n = 8 * 65536; out = Wqv; oidx = (long)(i >> 16) * 131072 + 65536 + (i & 65535); }
  else { in = wt;  n = 8 * 65536; out = Wt_; oidx = i; }
  if (i < n){
    f32x4 v = *(const f32x4*)(in + i);
    f16x4 o;
    o[0] = (f16)v[0]; o[1] = (f16)v[1]; o[2] = (f16)v[2]; o[3] = (f16)v[3];
    *(f16x4*)(out + oidx) = o;
  }
}

// ---------------- f32 [b][c][n] -> fp16 [b][n][c] ----------------
__global__ __launch_bounds__(256) void transpose_f16_k(const float* __restrict__ X,
                                                       f16* __restrict__ XT){
  __shared__ float tile[64][65];
  int b = blockIdx.z, c0 = blockIdx.y * 64, n0 = blockIdx.x * 64;
  int t = threadIdx.x, nl = t & 63, cr = t >> 6;
  long base = (long)b * 65536;
#pragma unroll
  for (int i = 0; i < 16; i++){
    int cl = cr + 4 * i;
    tile[cl][nl] = X[base + (c0 + cl) * 256 + (n0 + nl)];
  }
  __syncthreads();
  int cl2 = t & 63, nr2 = t >> 6;
#pragma unroll
  for (int i = 0; i < 16; i++){
    int nl2 = nr2 + 4 * i;
    XT[base + (n0 + nl2) * 256 + (c0 + cl2)] = (f16)tile[cl2][nl2];
  }
}

// ---------------- generic GEMM fp16 (gload_lds + XOR swizzle), round-7/10 verified ----------------
#define EPI_E    0
#define EPI_QV   1
#define EPI_Y16  2
#define EPI_C16  3
#define EPI_PVDT 4

template<int EPI>
__global__ __launch_bounds__(256) void gemm_f16(
    const f16* __restrict__ A, long sA,
    const f16* __restrict__ Bt,
    float* __restrict__ Cf, long sC,
    f16* __restrict__ Oh, f16* __restrict__ Oh2,
    const float* __restrict__ bias,
    const f16* __restrict__ Uh,
    float* __restrict__ Ps, float* __restrict__ Pq,
    float* __restrict__ Pm, float* __restrict__ Pp)
{
  constexpr bool BNST = (EPI == EPI_Y16) || (EPI == EPI_C16);
  __shared__ f16 As[128][64];
  __shared__ f16 Bs[128][64];
  int b  = blockIdx.z;
  int m0 = blockIdx.y * 128, n0 = blockIdx.x * 128;
  const f16* Ab = A  + (long)b * sA;
  const f16* Bb = Bt + (long)b * 65536;
  int t = threadIdx.x;
  int lane = t & 63, wid = t >> 6;
  int wm = (wid >> 1) * 64, wn = (wid & 1) * 64;
  f32x4 acc[4][4] = {};

  int lr = lane >> 3;
  int kc = ((lane & 7) ^ lr) * 8;   // inverse-swizzled global column

  for (int kt = 0; kt < 4; kt++){
    int k0 = kt * 64;
    if (kt) __syncthreads();
#pragma unroll
    for (int i = 0; i < 4; i++){
      int chunk = wid * 4 + i;
      int r = chunk * 8 + lr;
      GLOAD_LDS16(Ab + (m0 + r) * 256 + k0 + kc, &As[chunk * 8][0]);
      GLOAD_LDS16(Bb + (n0 + r) * 256 + k0 + kc, &Bs[chunk * 8][0]);
    }
    __syncthreads();
#pragma unroll
    for (int ks = 0; ks < 2; ks++){
      f16x8 af[4], bfr[4];
      int ko = ks * 32 + (lane >> 4) * 8;
#pragma unroll
      for (int mi = 0; mi < 4; mi++){
        int rA = wm + mi * 16 + (lane & 15);
        af[mi] = *(const f16x8*)(&As[rA][ko ^ ((rA & 7) << 3)]);
      }
#pragma unroll
      for (int ni = 0; ni < 4; ni++){
        int rB = wn + ni * 16 + (lane & 15);
        bfr[ni] = *(const f16x8*)(&Bs[rB][ko ^ ((rB & 7) << 3)]);
      }
#pragma unroll
      for (int mi = 0; mi < 4; mi++)
#pragma unroll
        for (int ni = 0; ni < 4; ni++)
          acc[mi][ni] = __builtin_amdgcn_mfma_f32_16x16x32_f16(af[mi], bfr[ni], acc[mi][ni], 0, 0, 0);
    }
  }

  float* ssum = (float*)&As[0][0];
  float* ssq  = ssum + 256;
  if constexpr (BNST) __syncthreads();

  int mg0 = m0 + wm + ((lane >> 4) << 2);
  int ng0 = n0 + wn + (lane & 15);

  if constexpr (EPI == EPI_E){
    float* Cb = Cf + (long)b * sC;
#pragma unroll
    for (int mi = 0; mi < 4; mi++){
      float lmax[4] = {-1e30f, -1e30f, -1e30f, -1e30f};
#pragma unroll
      for (int ni = 0; ni < 4; ni++){
        int mg = mg0 + mi * 16, ng = ng0 + ni * 16;
        f32x4 v = acc[mi][ni];
#pragma unroll
        for (int r = 0; r < 4; r++){ Cb[(mg + r) * 256 + ng] = v[r]; lmax[r] = fmaxf(lmax[r], v[r]); }
      }
#pragma unroll
      for (int r = 0; r < 4; r++){
        float m_ = lmax[r];
        m_ = fmaxf(m_, __shfl_xor(m_, 1)); m_ = fmaxf(m_, __shfl_xor(m_, 2));
        m_ = fmaxf(m_, __shfl_xor(m_, 4)); m_ = fmaxf(m_, __shfl_xor(m_, 8));
        float s_ = 0.f;
#pragma unroll
        for (int ni = 0; ni < 4; ni++) s_ += __expf(acc[mi][ni][r] - m_);
        s_ += __shfl_xor(s_, 1); s_ += __shfl_xor(s_, 2);
        s_ += __shfl_xor(s_, 4); s_ += __shfl_xor(s_, 8);
        if ((lane & 15) == 0){
          int row = mg0 + mi * 16 + r;
          long off = ((long)(b * 256 + row)) * 4 + blockIdx.x * 2 + (wid & 1);
          Pm[off] = m_; Pp[off] = s_;
        }
      }
    }
  } else if constexpr (EPI == EPI_QV){
    if (m0 < 256){
      f16* Ohb = Oh + (long)b * 65536;
#pragma unroll
      for (int mi = 0; mi < 4; mi++)
#pragma unroll
        for (int ni = 0; ni < 4; ni++){
          int mg = mg0 + mi * 16, ng = ng0 + ni * 16;
          f32x4 v = acc[mi][ni];
          f16x4 p;
#pragma unroll
          for (int r = 0; r < 4; r++) p[r] = (f16)v[r];
          *(f16x4*)(&Ohb[ng * 256 + mg]) = p;
        }
    } else {
      f16* Ohb = Oh2 + (long)b * 65536;
#pragma unroll
      for (int mi = 0; mi < 4; mi++)
#pragma unroll
        for (int ni = 0; ni < 4; ni++){
          int mg = mg0 + mi * 16 - 256, ng = ng0 + ni * 16;
          f32x4 v = acc[mi][ni];
#pragma unroll
          for (int r = 0; r < 4; r++) Ohb[(mg + r) * 256 + ng] = (f16)(v[r] + bias[mg + r]);
        }
    }
  } else if constexpr (EPI == EPI_PVDT){
    const f16* Ub = Uh + (long)b * 65536;
    f16* Ohb = Oh + (long)b * 65536;
#pragma unroll
    for (int mi = 0; mi < 4; mi++)
#pragma unroll
      for (int ni = 0; ni < 4; ni++){
        int mg = mg0 + mi * 16, ng = ng0 + ni * 16;
        f32x4 v = acc[mi][ni];
        f16x4 uv = *(const f16x4*)(&Ub[ng * 256 + mg]);
        f16x4 p;
#pragma unroll
        for (int r = 0; r < 4; r++) p[r] = (f16)((float)uv[r] - v[r]);
        *(f16x4*)(&Ohb[ng * 256 + mg]) = p;
      }
  } else { // EPI_Y16 / EPI_C16
    f16* Ohb = Oh + (long)b * 65536;
#pragma unroll
    for (int mi = 0; mi < 4; mi++){
      float sr[4] = {0.f, 0.f, 0.f, 0.f}, qr[4] = {0.f, 0.f, 0.f, 0.f};
#pragma unroll
      for (int ni = 0; ni < 4; ni++){
        int mg = mg0 + mi * 16, ng = ng0 + ni * 16;
        f32x4 v = acc[mi][ni];
#pragma unroll
        for (int r = 0; r < 4; r++){
          float vv = v[r];
          if constexpr (EPI == EPI_Y16) vv += bias[mg + r];
          f16 h = (f16)vv;
          float vf = (float)h;
          Ohb[(mg + r) * 256 + ng] = h;
          sr[r] += vf; qr[r] += vf * vf;
        }
      }
#pragma unroll
      for (int r = 0; r < 4; r++){
        float s = sr[r], q = qr[r];
        s += __shfl_xor(s, 1); q += __shfl_xor(q, 1);
        s += __shfl_xor(s, 2); q += __shfl_xor(q, 2);
        s += __shfl_xor(s, 4); q += __shfl_xor(q, 4);
        s += __shfl_xor(s, 8); q += __shfl_xor(q, 8);
        if ((lane & 15) == 0){
          int ch = wm + mi * 16 + (lane >> 4) * 4 + r;
          ssum[ch * 2 + (wid & 1)] = s;
          ssq [ch * 2 + (wid & 1)] = q;
        }
      }
    }
    __syncthreads();
    if (t < 128){
      int c = m0 + t;
      float S = ssum[t * 2] + ssum[t * 2 + 1];
      float Q = ssq [t * 2] + ssq [t * 2 + 1];
      long off = (long)c * 512 + b * 2 + blockIdx.x;
      Ps[off] = S; Pq[off] = Q;
    }
  }
}

// ---------------- fused smcomb + renorm (vectorized), round-11 verified ----------------
__global__ __launch_bounds__(256) void renorm2_k(const float* __restrict__ E,
                                                 const float* __restrict__ Pm,
                                                 const float* __restrict__ Pp,
                                                 f16* __restrict__ AT){
  __shared__ float smx[256], srs[256];
  int t = threadIdx.x;
  int rid0 = blockIdx.x * 4;
  int b = rid0 >> 8;
  {
    long pbase = ((long)(b * 256 + t)) * 4;
    f32x4 pm = *(const f32x4*)(Pm + pbase);
    f32x4 pp = *(const f32x4*)(Pp + pbase);
    float mm = fmaxf(fmaxf(pm[0], pm[1]), fmaxf(pm[2], pm[3]));
    float s = pp[0] * __expf(pm[0] - mm) + pp[1] * __expf(pm[1] - mm)
            + pp[2] * __expf(pm[2] - mm) + pp[3] * __expf(pm[3] - mm);
    smx[t] = mm; srs[t] = 1.f / s;
  }
  __syncthreads();
  int rid = rid0 + (t >> 6);
  int m = rid & 255;
  int lane = t & 63;
  f32x4 e = *(const f32x4*)(E + (long)b * 262144 + m * 256 + lane * 4);
  f32x4 mv = *(const f32x4*)(&smx[lane * 4]);
  f32x4 rv = *(const f32x4*)(&srs[lane * 4]);
  float tv[4];
  float cs = 0.f;
#pragma unroll
  for (int i = 0; i < 4; i++){ tv[i] = __expf(e[i] - mv[i]) * rv[i]; cs += tv[i]; }
  for (int off = 32; off > 0; off >>= 1) cs += __shfl_xor(cs, off);
  float inv = 1.f / (1e-9f + cs);
  f16x4 o;
#pragma unroll
  for (int i = 0; i < 4; i++) o[i] = (f16)(tv[i] * inv);
  *(f16x4*)(AT + (long)rid * 256 + lane * 4) = o;
}

// ---------------- BN apply + relu (+2x residual), stats computed in-block from Ps/Pq ----------------
// Replaces bn_reduce_k: 4 threads/channel sum the 512 partials (L2-resident), then
// identical normalize/relu/residual/layout-write as round 11 (vectorized f16x8/f32x4).
template<bool RESID, bool WN16, bool WT16, bool WDOUT>
__global__ __launch_bounds__(256) void bn_apply_k(
    const f16* __restrict__ Y, const f16* __restrict__ Uht,
    const float* __restrict__ Ps, const float* __restrict__ Pq,
    const float* __restrict__ gamma, const float* __restrict__ beta,
    f16* __restrict__ on16, f16* __restrict__ ot16,
    float* __restrict__ odout)
{
  __shared__ float tile[64][65];
  __shared__ float tileU[64][65];
  __shared__ float smean[64], srstd[64];
  int b = blockIdx.z, c0 = blockIdx.y * 64, n0 = blockIdx.x * 64;
  int t = threadIdx.x, rr = t >> 3, ss = t & 7;
  long base = (long)b * 65536;

  // --- stats from partials: 4 threads per channel, 128 partials each ---
  {
    int ch = t >> 2, part = t & 3;
    const float* ps = Ps + (long)(c0 + ch) * 512 + part * 128;
    const float* pq = Pq + (long)(c0 + ch) * 512 + part * 128;
    float s = 0.f, q = 0.f;
#pragma unroll
    for (int i = 0; i < 32; i++){
      f32x4 a = *(const f32x4*)(ps + i * 4);
      f32x4 c4 = *(const f32x4*)(pq + i * 4);
      s += a[0] + a[1] + a[2] + a[3];
      q += c4[0] + c4[1] + c4[2] + c4[3];
    }
    s += __shfl_xor(s, 1); q += __shfl_xor(q, 1);
    s += __shfl_xor(s, 2); q += __shfl_xor(q, 2);
    if (part == 0){
      float m = s * (1.f / 65536.f);
      float var = q * (1.f / 65536.f) - m * m;
      smean[ch] = m;
      srstd[ch] = rsqrtf(var + 1e-5f);
    }
  }
  if constexpr (RESID){
#pragma unroll
    for (int p = 0; p < 2; p++){
      int nl = rr + p * 32;
      f16x8 u = *(const f16x8*)(Uht + base + (n0 + nl) * 256 + c0 + ss * 8);
#pragma unroll
      for (int j = 0; j < 8; j++) tileU[ss * 8 + j][nl] = (float)u[j];
    }
  }
  __syncthreads();

#pragma unroll
  for (int p = 0; p < 2; p++){
    int cl = rr + p * 32;
    int c = c0 + cl;
    float mu = smean[cl], rg = srstd[cl] * gamma[c], be = beta[c];
    f16x8 y = *(const f16x8*)(Y + base + c * 256 + n0 + ss * 8);
    float v[8];
#pragma unroll
    for (int j = 0; j < 8; j++){
      float vv = fmaxf(((float)y[j] - mu) * rg + be, 0.f);
      if constexpr (RESID) vv += 2.f * tileU[cl][ss * 8 + j];
      v[j] = vv;
    }
    if constexpr (WN16){
      f16x8 h;
#pragma unroll
      for (int j = 0; j < 8; j++) h[j] = (f16)v[j];
      *(f16x8*)(on16 + base + c * 256 + n0 + ss * 8) = h;
    }
    if constexpr (WDOUT){
      f32x4 w0, w1;
#pragma unroll
      for (int j = 0; j < 4; j++){ w0[j] = v[j]; w1[j] = v[4 + j]; }
      float* od = odout + (long)b * 262144 + c * 256 + n0 + ss * 8;
      *(f32x4*)od = w0;
      *(f32x4*)(od + 4) = w1;
    }
    if constexpr (WT16){
#pragma unroll
      for (int j = 0; j < 8; j++) tile[cl][ss * 8 + j] = v[j];
    }
  }
  if constexpr (WT16){
    __syncthreads();
#pragma unroll
    for (int p = 0; p < 2; p++){
      int nl = rr + p * 32;
      f16x8 h;
#pragma unroll
      for (int j = 0; j < 8; j++) h[j] = (f16)tile[ss * 8 + j][nl];
      *(f16x8*)(ot16 + base + (n0 + nl) * 256 + c0 + ss * 8) = h;
    }
  }
}

extern "C" void kernel_launch(void* const* d_in, const int* in_sizes, int n_in,
                              void* d_out, int out_size, void* d_ws, size_t ws_size,
                              hipStream_t stream)
{
  (void)in_sizes; (void)n_in; (void)out_size; (void)ws_size;

  const float* x0  = (const float*)d_in[0];
  const float* cw  = (const float*)d_in[1];
  const float* bng = (const float*)d_in[2];
  const float* bnb = (const float*)d_in[3];
  const float* wqk = (const float*)d_in[4];
  const float* wv  = (const float*)d_in[5];
  const float* bv  = (const float*)d_in[6];
  const float* wt  = (const float*)d_in[7];
  const float* bt  = (const float*)d_in[8];
  const float* sag = (const float*)d_in[9];
  const float* sab = (const float*)d_in[10];

  const long T = 16777216; // elements per [B,C,N] tensor
  f16*  Ha  = (f16*)d_ws;          // operand ping
  f16*  Hb  = Ha + T;              // operand pong
  f16*  Yh  = Hb + T;              // pre-BN y (f16)
  f16*  XK  = Yh + T;              // xkT
  f16*  XV  = XK + T;              // xv
  f16*  ATb = XV + T;              // attnT fp16
  f16*  DT  = ATb + T;             // dT
  f16*  Wc  = DT + T;
  f16*  Wqv = Wc + 6 * 65536;      // stacked [Wq;Wv] per layer, 512x256
  f16*  Wt_ = Wqv + 16 * 65536;
  float* Ps = (float*)(Wt_ + 8 * 65536);  // [256][512] BN partial sums
  float* Pq = Ps + 131072;
  float* Pm = Pq + 131072;         // [65536][4] softmax partial max
  float* Pp = Pm + 262144;         // [65536][4] softmax partial sumexp
  float* E  = (float*)d_out + 196608; // d_out region 3 as energy scratch (batch stride 262144!)

  f16* H[2] = {Ha, Hb};
  int cur = 0;

  dim3 thr(256);
  dim3 gg(2, 2, 256);
  dim3 gqv(2, 4, 256);
  dim3 tile(4, 4, 256);

  cast_all_k<<<dim3(512, 4), thr, 0, stream>>>(cw, wqk, wv, wt, Wc, Wqv, Wt_);
  transpose_f16_k<<<tile, thr, 0, stream>>>(x0, H[0]);

  // conv0: next operand = (relu(bn(W x)))^T
  gemm_f16<EPI_C16><<<gg, thr, 0, stream>>>(Wc, 0, H[cur], nullptr, 0, Yh, nullptr, nullptr, nullptr, Ps, Pq, nullptr, nullptr);
  bn_apply_k<false, false, true, false><<<tile, thr, 0, stream>>>(
      Yh, nullptr, Ps, Pq, bng, bnb, nullptr, H[cur ^ 1], nullptr);
  cur ^= 1;
  // conv1
  gemm_f16<EPI_C16><<<gg, thr, 0, stream>>>(Wc + 65536, 0, H[cur], nullptr, 0, Yh, nullptr, nullptr, nullptr, Ps, Pq, nullptr, nullptr);
  bn_apply_k<false, false, true, false><<<tile, thr, 0, stream>>>(
      Yh, nullptr, Ps, Pq, bng + 256, bnb + 256, nullptr, H[cur ^ 1], nullptr);
  cur ^= 1;

  for (int blk = 0; blk < 4; blk++){
    for (int s = 0; s < 2; s++){
      int li = 2 * blk + s;
      f16* Hc = H[cur];
      f16* Hn = H[cur ^ 1];
      // xkT (transposed) + xv (+bias) in one dispatch
      gemm_f16<EPI_QV><<<gqv, thr, 0, stream>>>(Wqv + (long)li * 131072, 0, Hc, nullptr, 0,
                                                XK, XV, bv + li * 256, nullptr, nullptr, nullptr, nullptr, nullptr);
      // E = Xk^T Xk (f32, symmetric) + softmax row partials
      gemm_f16<EPI_E><<<gg, thr, 0, stream>>>(XK, 65536, XK, E, 262144,
                                              nullptr, nullptr, nullptr, nullptr, nullptr, nullptr, Pm, Pp);
      // fused smcomb + renorm
      renorm2_k<<<dim3(16384), thr, 0, stream>>>(E, Pm, Pp, ATb);
      // dT = (u - xv attn')^T; u read from Hc (f16, contiguous)
      gemm_f16<EPI_PVDT><<<gg, thr, 0, stream>>>(XV, 65536, ATb, nullptr, 0,
                                                 DT, nullptr, nullptr, Hc, nullptr, nullptr, nullptr, nullptr);
      // y = wt d + bt -> Yh f16 (+ fused BN partials)
      gemm_f16<EPI_Y16><<<gg, thr, 0, stream>>>(Wt_ + (long)li * 65536, 0, DT, nullptr, 0,
                                                Yh, nullptr, bt + li * 256, nullptr, Ps, Pq, nullptr, nullptr);
      if (s == 0){
        // x1 = 2u + relu(bn(y)); Hn <- x1 normal (next operand)
        bn_apply_k<true, true, false, false><<<tile, thr, 0, stream>>>(
            Yh, Hc, Ps, Pq, sag + li * 256, sab + li * 256, Hn, nullptr, nullptr);
      } else {
        // x11pre = 2u + relu(bn(y)); Hn <- transposed (next operand for block conv)
        bn_apply_k<true, false, true, false><<<tile, thr, 0, stream>>>(
            Yh, Hc, Ps, Pq, sag + li * 256, sab + li * 256, nullptr, Hn, nullptr);
      }
      cur ^= 1;
    }
    // block conv + bn + relu -> d_out region blk + next operand (transposed)
    gemm_f16<EPI_C16><<<gg, thr, 0, stream>>>(Wc + (long)(blk + 2) * 65536, 0, H[cur], nullptr, 0,
                                              Yh, nullptr, nullptr, nullptr, Ps, Pq, nullptr, nullptr);
    bn_apply_k<false, false, true, true><<<tile, thr, 0, stream>>>(
        Yh, nullptr, Ps, Pq, bng + (blk + 2) * 256, bnb + (blk + 2) * 256,
        nullptr, H[cur ^ 1], (float*)d_out + blk * 65536);
    cur ^= 1;
  }
}

// Round 14
// 1802.298 us; speedup vs baseline: 1.8841x; 1.8841x over previous
//
#include <hip/hip_runtime.h>
#include <hip/hip_bf16.h>

typedef _Float16 f16;
typedef __attribute__((ext_vector_type(8))) _Float16 f16x8;
typedef __attribute__((ext_vector_type(4))) _Float16 f16x4;
typedef __attribute__((ext_vector_type(4))) float f32x4;

#define GLOAD_LDS16(gp, lp) \
  __builtin_amdgcn_global_load_lds((const __attribute__((address_space(1))) void*)(gp), \
                                   (__attribute__((address_space(3))) void*)(lp), 16, 0, 0)

// ---------------- all weight casts in one dispatch; wqk/wv stacked into Wqv ----------------
__global__ __launch_bounds__(256) void cast_all_k(const float* __restrict__ cw,
                                                  const float* __restrict__ wqk,
                                                  const float* __restrict__ wv,
                                                  const float* __restrict__ wt,
                                                  f16* __restrict__ Wc, f16* __restrict__ Wqv,
                                                  f16* __restrict__ Wt_){
  int y = blockIdx.y;
  int i = (blockIdx.x * 256 + threadIdx.x) * 4;
  const float* in; f16* out; int n; long oidx;
  if (y == 0){ in = cw;  n = 6 * 65536; out = Wc;  oidx = i; }
  else if (y == 1){ in = wqk; n = 8 * 65536; out = Wqv; oidx = (long)(i >> 16) * 131072 + (i & 65535); }
  else if (y == 2){ in = wv;  n = 8 * 65536; out = Wqv; oidx = (long)(i >> 16) * 131072 + 65536 + (i & 65535); }
  else { in = wt;  n = 8 * 65536; out = Wt_; oidx = i; }
  if (i < n){
    f32x4 v = *(const f32x4*)(in + i);
    f16x4 o;
    o[0] = (f16)v[0]; o[1] = (f16)v[1]; o[2] = (f16)v[2]; o[3] = (f16)v[3];
    *(f16x4*)(out + oidx) = o;
  }
}

// ---------------- f32 [b][c][n] -> fp16 [b][n][c] ----------------
__global__ __launch_bounds__(256) void transpose_f16_k(const float* __restrict__ X,
                                                       f16* __restrict__ XT){
  __shared__ float tile[64][65];
  int b = blockIdx.z, c0 = blockIdx.y * 64, n0 = blockIdx.x * 64;
  int t = threadIdx.x, nl = t & 63, cr = t >> 6;
  long base = (long)b * 65536;
#pragma unroll
  for (int i = 0; i < 16; i++){
    int cl = cr + 4 * i;
    tile[cl][nl] = X[base + (c0 + cl) * 256 + (n0 + nl)];
  }
  __syncthreads();
  int cl2 = t & 63, nr2 = t >> 6;
#pragma unroll
  for (int i = 0; i < 16; i++){
    int nl2 = nr2 + 4 * i;
    XT[base + (n0 + nl2) * 256 + (c0 + cl2)] = (f16)tile[cl2][nl2];
  }
}

// ---------------- generic GEMM fp16 (gload_lds + XOR swizzle), round-7/10 verified ----------------
// EPI_E stores Etilde = E - quadmax (f16, batch stride 65536) + softmax row partials Pm/Pp.
#define EPI_E    0
#define EPI_QV   1
#define EPI_Y16  2
#define EPI_C16  3
#define EPI_PVDT 4

template<int EPI>
__global__ __launch_bounds__(256) void gemm_f16(
    const f16* __restrict__ A, long sA,
    const f16* __restrict__ Bt,
    f16* __restrict__ Oh, f16* __restrict__ Oh2,
    const float* __restrict__ bias,
    const f16* __restrict__ Uh,
    float* __restrict__ Ps, float* __restrict__ Pq,
    float* __restrict__ Pm, float* __restrict__ Pp)
{
  constexpr bool BNST = (EPI == EPI_Y16) || (EPI == EPI_C16);
  __shared__ f16 As[128][64];
  __shared__ f16 Bs[128][64];
  int b  = blockIdx.z;
  int m0 = blockIdx.y * 128, n0 = blockIdx.x * 128;
  const f16* Ab = A  + (long)b * sA;
  const f16* Bb = Bt + (long)b * 65536;
  int t = threadIdx.x;
  int lane = t & 63, wid = t >> 6;
  int wm = (wid >> 1) * 64, wn = (wid & 1) * 64;
  f32x4 acc[4][4] = {};

  int lr = lane >> 3;
  int kc = ((lane & 7) ^ lr) * 8;   // inverse-swizzled global column

  for (int kt = 0; kt < 4; kt++){
    int k0 = kt * 64;
    if (kt) __syncthreads();
#pragma unroll
    for (int i = 0; i < 4; i++){
      int chunk = wid * 4 + i;
      int r = chunk * 8 + lr;
      GLOAD_LDS16(Ab + (m0 + r) * 256 + k0 + kc, &As[chunk * 8][0]);
      GLOAD_LDS16(Bb + (n0 + r) * 256 + k0 + kc, &Bs[chunk * 8][0]);
    }
    __syncthreads();
#pragma unroll
    for (int ks = 0; ks < 2; ks++){
      f16x8 af[4], bfr[4];
      int ko = ks * 32 + (lane >> 4) * 8;
#pragma unroll
      for (int mi = 0; mi < 4; mi++){
        int rA = wm + mi * 16 + (lane & 15);
        af[mi] = *(const f16x8*)(&As[rA][ko ^ ((rA & 7) << 3)]);
      }
#pragma unroll
      for (int ni = 0; ni < 4; ni++){
        int rB = wn + ni * 16 + (lane & 15);
        bfr[ni] = *(const f16x8*)(&Bs[rB][ko ^ ((rB & 7) << 3)]);
      }
#pragma unroll
      for (int mi = 0; mi < 4; mi++)
#pragma unroll
        for (int ni = 0; ni < 4; ni++)
          acc[mi][ni] = __builtin_amdgcn_mfma_f32_16x16x32_f16(af[mi], bfr[ni], acc[mi][ni], 0, 0, 0);
    }
  }

  float* ssum = (float*)&As[0][0];
  float* ssq  = ssum + 256;
  if constexpr (BNST) __syncthreads();

  int mg0 = m0 + wm + ((lane >> 4) << 2);
  int ng0 = n0 + wn + (lane & 15);

  if constexpr (EPI == EPI_E){
    f16* Eb = Oh + (long)b * 65536;
#pragma unroll
    for (int mi = 0; mi < 4; mi++){
      float lmax[4] = {-1e30f, -1e30f, -1e30f, -1e30f};
#pragma unroll
      for (int ni = 0; ni < 4; ni++){
#pragma unroll
        for (int r = 0; r < 4; r++) lmax[r] = fmaxf(lmax[r], acc[mi][ni][r]);
      }
#pragma unroll
      for (int r = 0; r < 4; r++){
        float m_ = lmax[r];
        m_ = fmaxf(m_, __shfl_xor(m_, 1)); m_ = fmaxf(m_, __shfl_xor(m_, 2));
        m_ = fmaxf(m_, __shfl_xor(m_, 4)); m_ = fmaxf(m_, __shfl_xor(m_, 8));
        int mg = mg0 + mi * 16 + r;
        float s_ = 0.f;
#pragma unroll
        for (int ni = 0; ni < 4; ni++){
          float d = acc[mi][ni][r] - m_;      // <= 0, small where it matters
          s_ += __expf(d);
          Eb[mg * 256 + ng0 + ni * 16] = (f16)d;
        }
        s_ += __shfl_xor(s_, 1); s_ += __shfl_xor(s_, 2);
        s_ += __shfl_xor(s_, 4); s_ += __shfl_xor(s_, 8);
        if ((lane & 15) == 0){
          long off = ((long)(b * 256 + mg)) * 4 + blockIdx.x * 2 + (wid & 1);
          Pm[off] = m_; Pp[off] = s_;
        }
      }
    }
  } else if constexpr (EPI == EPI_QV){
    if (m0 < 256){
      f16* Ohb = Oh + (long)b * 65536;
#pragma unroll
      for (int mi = 0; mi < 4; mi++)
#pragma unroll
        for (int ni = 0; ni < 4; ni++){
          int mg = mg0 + mi * 16, ng = ng0 + ni * 16;
          f32x4 v = acc[mi][ni];
          f16x4 p;
#pragma unroll
          for (int r = 0; r < 4; r++) p[r] = (f16)v[r];
          *(f16x4*)(&Ohb[ng * 256 + mg]) = p;
        }
    } else {
      f16* Ohb = Oh2 + (long)b * 65536;
#pragma unroll
      for (int mi = 0; mi < 4; mi++)
#pragma unroll
        for (int ni = 0; ni < 4; ni++){
          int mg = mg0 + mi * 16 - 256, ng = ng0 + ni * 16;
          f32x4 v = acc[mi][ni];
#pragma unroll
          for (int r = 0; r < 4; r++) Ohb[(mg + r) * 256 + ng] = (f16)(v[r] + bias[mg + r]);
        }
    }
  } else if constexpr (EPI == EPI_PVDT){
    const f16* Ub = Uh + (long)b * 65536;
    f16* Ohb = Oh + (long)b * 65536;
#pragma unroll
    for (int mi = 0; mi < 4; mi++)
#pragma unroll
      for (int ni = 0; ni < 4; ni++){
        int mg = mg0 + mi * 16, ng = ng0 + ni * 16;
        f32x4 v = acc[mi][ni];
        f16x4 uv = *(const f16x4*)(&Ub[ng * 256 + mg]);
        f16x4 p;
#pragma unroll
        for (int r = 0; r < 4; r++) p[r] = (f16)((float)uv[r] - v[r]);
        *(f16x4*)(&Ohb[ng * 256 + mg]) = p;
      }
  } else { // EPI_Y16 / EPI_C16
    f16* Ohb = Oh + (long)b * 65536;
#pragma unroll
    for (int mi = 0; mi < 4; mi++){
      float sr[4] = {0.f, 0.f, 0.f, 0.f}, qr[4] = {0.f, 0.f, 0.f, 0.f};
#pragma unroll
      for (int ni = 0; ni < 4; ni++){
        int mg = mg0 + mi * 16, ng = ng0 + ni * 16;
        f32x4 v = acc[mi][ni];
#pragma unroll
        for (int r = 0; r < 4; r++){
          float vv = v[r];
          if constexpr (EPI == EPI_Y16) vv += bias[mg + r];
          f16 h = (f16)vv;
          float vf = (float)h;
          Ohb[(mg + r) * 256 + ng] = h;
          sr[r] += vf; qr[r] += vf * vf;
        }
      }
#pragma unroll
      for (int r = 0; r < 4; r++){
        float s = sr[r], q = qr[r];
        s += __shfl_xor(s, 1); q += __shfl_xor(q, 1);
        s += __shfl_xor(s, 2); q += __shfl_xor(q, 2);
        s += __shfl_xor(s, 4); q += __shfl_xor(q, 4);
        s += __shfl_xor(s, 8); q += __shfl_xor(q, 8);
        if ((lane & 15) == 0){
          int ch = wm + mi * 16 + (lane >> 4) * 4 + r;
          ssum[ch * 2 + (wid & 1)] = s;
          ssq [ch * 2 + (wid & 1)] = q;
        }
      }
    }
    __syncthreads();
    if (t < 128){
      int c = m0 + t;
      float S = ssum[t * 2] + ssum[t * 2 + 1];
      float Q = ssq [t * 2] + ssq [t * 2 + 1];
      long off = (long)c * 512 + b * 2 + blockIdx.x;
      Ps[off] = S; Pq[off] = Q;
    }
  }
}

// ---------------- finalize BN stats from per-block partials (round-11 verified) ----------------
__global__ __launch_bounds__(256) void bn_reduce_k(const float* __restrict__ Ps,
                                                   const float* __restrict__ Pq,
                                                   float* __restrict__ mean, float* __restrict__ rstd){
  int c = blockIdx.x, t = threadIdx.x;
  float s = Ps[c * 512 + t] + Ps[c * 512 + t + 256];
  float q = Pq[c * 512 + t] + Pq[c * 512 + t + 256];
  for (int off = 32; off > 0; off >>= 1){ s += __shfl_down(s, off); q += __shfl_down(q, off); }
  __shared__ float ss[4], qq[4];
  int lane = t & 63, w = t >> 6;
  if (lane == 0){ ss[w] = s; qq[w] = q; }
  __syncthreads();
  if (t == 0){
    float S = ss[0] + ss[1] + ss[2] + ss[3];
    float Q = qq[0] + qq[1] + qq[2] + qq[3];
    float m = S * (1.f / 65536.f);
    float var = Q * (1.f / 65536.f) - m * m;
    mean[c] = m;
    rstd[c] = rsqrtf(var + 1e-5f);
  }
}

// ---------------- fused smcomb + renorm; E holds Etilde = E - Pm[row][quad] (f16) ----------------
// exponent reconstructed in f32: Etilde + Pm[row][q] - mx[n]  (== E - mx[n] exactly, <= 0)
__global__ __launch_bounds__(256) void renorm2_k(const f16* __restrict__ E,
                                                 const float* __restrict__ Pm,
                                                 const float* __restrict__ Pp,
                                                 f16* __restrict__ AT){
  __shared__ float smx[256], srs[256];
  int t = threadIdx.x;
  int rid0 = blockIdx.x * 4;
  int b = rid0 >> 8;
  {
    long pbase = ((long)(b * 256 + t)) * 4;
    f32x4 pm = *(const f32x4*)(Pm + pbase);
    f32x4 pp = *(const f32x4*)(Pp + pbase);
    float mm = fmaxf(fmaxf(pm[0], pm[1]), fmaxf(pm[2], pm[3]));
    float s = pp[0] * __expf(pm[0] - mm) + pp[1] * __expf(pm[1] - mm)
            + pp[2] * __expf(pm[2] - mm) + pp[3] * __expf(pm[3] - mm);
    smx[t] = mm; srs[t] = 1.f / s;
  }
  __syncthreads();
  int rid = rid0 + (t >> 6);
  int m = rid & 255;
  int lane = t & 63;
  int q = lane >> 4;                       // columns lane*4..lane*4+3 all in quadrant q
  float pmrow = Pm[(long)(b * 256 + m) * 4 + q];
  f16x4 e4 = *(const f16x4*)(E + (long)b * 65536 + m * 256 + lane * 4);
  f32x4 mv = *(const f32x4*)(&smx[lane * 4]);
  f32x4 rv = *(const f32x4*)(&srs[lane * 4]);
  float tv[4];
  float cs = 0.f;
#pragma unroll
  for (int i = 0; i < 4; i++){
    tv[i] = __expf((float)e4[i] + pmrow - mv[i]) * rv[i];
    cs += tv[i];
  }
  for (int off = 32; off > 0; off >>= 1) cs += __shfl_xor(cs, off);
  float inv = 1.f / (1e-9f + cs);
  f16x4 o;
#pragma unroll
  for (int i = 0; i < 4; i++) o[i] = (f16)(tv[i] * inv);
  *(f16x4*)(AT + (long)rid * 256 + lane * 4) = o;
}

// ---------------- BN apply + relu (+2x residual), vectorized (round-11 verified) ----------------
template<bool RESID, bool WN16, bool WT16, bool WDOUT>
__global__ __launch_bounds__(256) void bn_apply_k(
    const f16* __restrict__ Y, const f16* __restrict__ Uht,
    const float* __restrict__ mean, const float* __restrict__ rstd,
    const float* __restrict__ gamma, const float* __restrict__ beta,
    f16* __restrict__ on16, f16* __restrict__ ot16,
    float* __restrict__ odout)
{
  __shared__ float tile[64][65];
  __shared__ float tileU[64][65];
  int b = blockIdx.z, c0 = blockIdx.y * 64, n0 = blockIdx.x * 64;
  int t = threadIdx.x, rr = t >> 3, ss = t & 7;
  long base = (long)b * 65536;
  if constexpr (RESID){
#pragma unroll
    for (int p = 0; p < 2; p++){
      int nl = rr + p * 32;
      f16x8 u = *(const f16x8*)(Uht + base + (n0 + nl) * 256 + c0 + ss * 8);
#pragma unroll
      for (int j = 0; j < 8; j++) tileU[ss * 8 + j][nl] = (float)u[j];
    }
    __syncthreads();
  }
#pragma unroll
  for (int p = 0; p < 2; p++){
    int cl = rr + p * 32;
    int c = c0 + cl;
    float mu = mean[c], rg = rstd[c] * gamma[c], be = beta[c];
    f16x8 y = *(const f16x8*)(Y + base + c * 256 + n0 + ss * 8);
    float v[8];
#pragma unroll
    for (int j = 0; j < 8; j++){
      float vv = fmaxf(((float)y[j] - mu) * rg + be, 0.f);
      if constexpr (RESID) vv += 2.f * tileU[cl][ss * 8 + j];
      v[j] = vv;
    }
    if constexpr (WN16){
      f16x8 h;
#pragma unroll
      for (int j = 0; j < 8; j++) h[j] = (f16)v[j];
      *(f16x8*)(on16 + base + c * 256 + n0 + ss * 8) = h;
    }
    if constexpr (WDOUT){
      f32x4 w0, w1;
#pragma unroll
      for (int j = 0; j < 4; j++){ w0[j] = v[j]; w1[j] = v[4 + j]; }
      float* od = odout + (long)b * 262144 + c * 256 + n0 + ss * 8;
      *(f32x4*)od = w0;
      *(f32x4*)(od + 4) = w1;
    }
    if constexpr (WT16){
#pragma unroll
      for (int j = 0; j < 8; j++) tile[cl][ss * 8 + j] = v[j];
    }
  }
  if constexpr (WT16){
    __syncthreads();
#pragma unroll
    for (int p = 0; p < 2; p++){
      int nl = rr + p * 32;
      f16x8 h;
#pragma unroll
      for (int j = 0; j < 8; j++) h[j] = (f16)tile[ss * 8 + j][nl];
      *(f16x8*)(ot16 + base + (n0 + nl) * 256 + c0 + ss * 8) = h;
    }
  }
}

extern "C" void kernel_launch(void* const* d_in, const int* in_sizes, int n_in,
                              void* d_out, int out_size, void* d_ws, size_t ws_size,
                              hipStream_t stream)
{
  (void)in_sizes; (void)n_in; (void)out_size; (void)ws_size;

  const float* x0  = (const float*)d_in[0];
  const float* cw  = (const float*)d_in[1];
  const float* bng = (const float*)d_in[2];
  const float* bnb = (const float*)d_in[3];
  const float* wqk = (const float*)d_in[4];
  const float* wv  = (const float*)d_in[5];
  const float* bv  = (const float*)d_in[6];
  const float* wt  = (const float*)d_in[7];
  const float* bt  = (const float*)d_in[8];
  const float* sag = (const float*)d_in[9];
  const float* sab = (const float*)d_in[10];

  const long T = 16777216; // elements per [B,C,N] tensor
  f16*  Ha  = (f16*)d_ws;          // operand ping
  f16*  Hb  = Ha + T;              // operand pong
  f16*  Yh  = Hb + T;              // pre-BN y (f16)
  f16*  XK  = Yh + T;              // xkT
  f16*  XV  = XK + T;              // xv
  f16*  ATb = XV + T;              // attnT fp16
  f16*  DT  = ATb + T;             // dT
  f16*  Eh  = DT + T;              // Etilde f16 [B][256][256]
  f16*  Wc  = Eh + T;
  f16*  Wqv = Wc + 6 * 65536;      // stacked [Wq;Wv] per layer, 512x256
  f16*  Wt_ = Wqv + 16 * 65536;
  float* mn = (float*)(Wt_ + 8 * 65536);
  float* rsd = mn + 256;
  float* Ps = rsd + 256;           // [256][512] BN partial sums
  float* Pq = Ps + 131072;
  float* Pm = Pq + 131072;         // [65536][4] softmax partial max (quadrant max)
  float* Pp = Pm + 262144;         // [65536][4] softmax partial sumexp

  f16* H[2] = {Ha, Hb};
  int cur = 0;

  dim3 thr(256);
  dim3 gg(2, 2, 256);
  dim3 gqv(2, 4, 256);
  dim3 tile(4, 4, 256);

  cast_all_k<<<dim3(512, 4), thr, 0, stream>>>(cw, wqk, wv, wt, Wc, Wqv, Wt_);
  transpose_f16_k<<<tile, thr, 0, stream>>>(x0, H[0]);

  // conv0: next operand = (relu(bn(W x)))^T
  gemm_f16<EPI_C16><<<gg, thr, 0, stream>>>(Wc, 0, H[cur], Yh, nullptr, nullptr, nullptr, Ps, Pq, nullptr, nullptr);
  bn_reduce_k<<<256, thr, 0, stream>>>(Ps, Pq, mn, rsd);
  bn_apply_k<false, false, true, false><<<tile, thr, 0, stream>>>(
      Yh, nullptr, mn, rsd, bng, bnb, nullptr, H[cur ^ 1], nullptr);
  cur ^= 1;
  // conv1
  gemm_f16<EPI_C16><<<gg, thr, 0, stream>>>(Wc + 65536, 0, H[cur], Yh, nullptr, nullptr, nullptr, Ps, Pq, nullptr, nullptr);
  bn_reduce_k<<<256, thr, 0, stream>>>(Ps, Pq, mn, rsd);
  bn_apply_k<false, false, true, false><<<tile, thr, 0, stream>>>(
      Yh, nullptr, mn, rsd, bng + 256, bnb + 256, nullptr, H[cur ^ 1], nullptr);
  cur ^= 1;

  for (int blk = 0; blk < 4; blk++){
    for (int s = 0; s < 2; s++){
      int li = 2 * blk + s;
      f16* Hc = H[cur];
      f16* Hn = H[cur ^ 1];
      // xkT (transposed) + xv (+bias) in one dispatch
      gemm_f16<EPI_QV><<<gqv, thr, 0, stream>>>(Wqv + (long)li * 131072, 0, Hc,
                                                XK, XV, bv + li * 256, nullptr, nullptr, nullptr, nullptr, nullptr);
      // Etilde = E - quadmax (f16) + softmax row partials
      gemm_f16<EPI_E><<<gg, thr, 0, stream>>>(XK, 65536, XK,
                                              Eh, nullptr, nullptr, nullptr, nullptr, nullptr, Pm, Pp);
      // fused smcomb + renorm (reconstructs exact exponent in f32)
      renorm2_k<<<dim3(16384), thr, 0, stream>>>(Eh, Pm, Pp, ATb);
      // dT = (u - xv attn')^T; u read from Hc (f16, contiguous)
      gemm_f16<EPI_PVDT><<<gg, thr, 0, stream>>>(XV, 65536, ATb,
                                                 DT, nullptr, nullptr, Hc, nullptr, nullptr, nullptr, nullptr);
      // y = wt d + bt -> Yh f16 (+ fused BN partials)
      gemm_f16<EPI_Y16><<<gg, thr, 0, stream>>>(Wt_ + (long)li * 65536, 0, DT,
                                                Yh, nullptr, bt + li * 256, nullptr, Ps, Pq, nullptr, nullptr);
      bn_reduce_k<<<256, thr, 0, stream>>>(Ps, Pq, mn, rsd);
      if (s == 0){
        // x1 = 2u + relu(bn(y)); Hn <- x1 normal (next operand)
        bn_apply_k<true, true, false, false><<<tile, thr, 0, stream>>>(
            Yh, Hc, mn, rsd, sag + li * 256, sab + li * 256, Hn, nullptr, nullptr);
      } else {
        // x11pre = 2u + relu(bn(y)); Hn <- transposed (next operand for block conv)
        bn_apply_k<true, false, true, false><<<tile, thr, 0, stream>>>(
            Yh, Hc, mn, rsd, sag + li * 256, sab + li * 256, nullptr, Hn, nullptr);
      }
      cur ^= 1;
    }
    // block conv + bn + relu -> d_out region blk + next operand (transposed)
    gemm_f16<EPI_C16><<<gg, thr, 0, stream>>>(Wc + (long)(blk + 2) * 65536, 0, H[cur],
                                              Yh, nullptr, nullptr, nullptr, Ps, Pq, nullptr, nullptr);
    bn_reduce_k<<<256, thr, 0, stream>>>(Ps, Pq, mn, rsd);
    bn_apply_k<false, false, true, true><<<tile, thr, 0, stream>>>(
        Yh, nullptr, mn, rsd, bng + (blk + 2) * 256, bnb + (blk + 2) * 256,
        nullptr, H[cur ^ 1], (float*)d_out + blk * 65536);
    cur ^= 1;
  }
}

// Round 15
// 1659.774 us; speedup vs baseline: 2.0459x; 1.0859x over previous
//
#include <hip/hip_runtime.h>
#include <hip/hip_bf16.h>

typedef _Float16 f16;
typedef __attribute__((ext_vector_type(8))) _Float16 f16x8;
typedef __attribute__((ext_vector_type(4))) _Float16 f16x4;
typedef __attribute__((ext_vector_type(4))) float f32x4;

#define GLOAD_LDS16(gp, lp) \
  __builtin_amdgcn_global_load_lds((const __attribute__((address_space(1))) void*)(gp), \
                                   (__attribute__((address_space(3))) void*)(lp), 16, 0, 0)

// ---------------- all weight casts in one dispatch; wqk/wv stacked into Wqv ----------------
__global__ __launch_bounds__(256) void cast_all_k(const float* __restrict__ cw,
                                                  const float* __restrict__ wqk,
                                                  const float* __restrict__ wv,
                                                  const float* __restrict__ wt,
                                                  f16* __restrict__ Wc, f16* __restrict__ Wqv,
                                                  f16* __restrict__ Wt_){
  int y = blockIdx.y;
  int i = (blockIdx.x * 256 + threadIdx.x) * 4;
  const float* in; f16* out; int n; long oidx;
  if (y == 0){ in = cw;  n = 6 * 65536; out = Wc;  oidx = i; }
  else if (y == 1){ in = wqk; n = 8 * 65536; out = Wqv; oidx = (long)(i >> 16) * 131072 + (i & 65535); }
  else if (y == 2){ in = wv;  n = 8 * 65536; out = Wqv; oidx = (long)(i >> 16) * 131072 + 65536 + (i & 65535); }
  else { in = wt;  n = 8 * 65536; out = Wt_; oidx = i; }
  if (i < n){
    f32x4 v = *(const f32x4*)(in + i);
    f16x4 o;
    o[0] = (f16)v[0]; o[1] = (f16)v[1]; o[2] = (f16)v[2]; o[3] = (f16)v[3];
    *(f16x4*)(out + oidx) = o;
  }
}

// ---------------- f32 [b][c][n] -> fp16 [b][n][c] ----------------
__global__ __launch_bounds__(256) void transpose_f16_k(const float* __restrict__ X,
                                                       f16* __restrict__ XT){
  __shared__ float tile[64][65];
  int b = blockIdx.z, c0 = blockIdx.y * 64, n0 = blockIdx.x * 64;
  int t = threadIdx.x, nl = t & 63, cr = t >> 6;
  long base = (long)b * 65536;
#pragma unroll
  for (int i = 0; i < 16; i++){
    int cl = cr + 4 * i;
    tile[cl][nl] = X[base + (c0 + cl) * 256 + (n0 + nl)];
  }
  __syncthreads();
  int cl2 = t & 63, nr2 = t >> 6;
#pragma unroll
  for (int i = 0; i < 16; i++){
    int nl2 = nr2 + 4 * i;
    XT[base + (n0 + nl2) * 256 + (c0 + cl2)] = (f16)tile[cl2][nl2];
  }
}

// ---------------- generic GEMM fp16 (gload_lds + XOR swizzle), round-7/10/14 verified ----------------
// XCD swizzle: batch b pinned to XCD b%8 (bijective decode of the linear dispatch index).
// EPI_E stores Etilde = E - quadmax (f16, batch stride 65536) + softmax row partials Pm/Pp.
#define EPI_E    0
#define EPI_QV   1
#define EPI_Y16  2
#define EPI_C16  3
#define EPI_PVDT 4

template<int EPI>
__global__ __launch_bounds__(256) void gemm_f16(
    const f16* __restrict__ A, long sA,
    const f16* __restrict__ Bt,
    f16* __restrict__ Oh, f16* __restrict__ Oh2,
    const float* __restrict__ bias,
    const f16* __restrict__ Uh,
    float* __restrict__ Ps, float* __restrict__ Pq,
    float* __restrict__ Pm, float* __restrict__ Pp)
{
  constexpr bool BNST = (EPI == EPI_Y16) || (EPI == EPI_C16);
  __shared__ f16 As[128][64];
  __shared__ f16 Bs[128][64];
  // --- XCD-aware decode: d%8 == b%8 for every tile of batch b ---
  int d = blockIdx.x + gridDim.x * (blockIdx.y + gridDim.y * blockIdx.z);
  int nq = gridDim.x * gridDim.y;          // tiles per batch (4 or 8)
  int xcd = d & 7, rem = d >> 3;
  int q = rem % nq, zhi = rem / nq;
  int b = xcd + 8 * zhi;
  int tx = q % gridDim.x, ty = q / gridDim.x;
  int m0 = ty * 128, n0 = tx * 128;
  const f16* Ab = A  + (long)b * sA;
  const f16* Bb = Bt + (long)b * 65536;
  int t = threadIdx.x;
  int lane = t & 63, wid = t >> 6;
  int wm = (wid >> 1) * 64, wn = (wid & 1) * 64;
  f32x4 acc[4][4] = {};

  int lr = lane >> 3;
  int kc = ((lane & 7) ^ lr) * 8;   // inverse-swizzled global column

  for (int kt = 0; kt < 4; kt++){
    int k0 = kt * 64;
    if (kt) __syncthreads();
#pragma unroll
    for (int i = 0; i < 4; i++){
      int chunk = wid * 4 + i;
      int r = chunk * 8 + lr;
      GLOAD_LDS16(Ab + (m0 + r) * 256 + k0 + kc, &As[chunk * 8][0]);
      GLOAD_LDS16(Bb + (n0 + r) * 256 + k0 + kc, &Bs[chunk * 8][0]);
    }
    __syncthreads();
#pragma unroll
    for (int ks = 0; ks < 2; ks++){
      f16x8 af[4], bfr[4];
      int ko = ks * 32 + (lane >> 4) * 8;
#pragma unroll
      for (int mi = 0; mi < 4; mi++){
        int rA = wm + mi * 16 + (lane & 15);
        af[mi] = *(const f16x8*)(&As[rA][ko ^ ((rA & 7) << 3)]);
      }
#pragma unroll
      for (int ni = 0; ni < 4; ni++){
        int rB = wn + ni * 16 + (lane & 15);
        bfr[ni] = *(const f16x8*)(&Bs[rB][ko ^ ((rB & 7) << 3)]);
      }
#pragma unroll
      for (int mi = 0; mi < 4; mi++)
#pragma unroll
        for (int ni = 0; ni < 4; ni++)
          acc[mi][ni] = __builtin_amdgcn_mfma_f32_16x16x32_f16(af[mi], bfr[ni], acc[mi][ni], 0, 0, 0);
    }
  }

  float* ssum = (float*)&As[0][0];
  float* ssq  = ssum + 256;
  if constexpr (BNST) __syncthreads();

  int mg0 = m0 + wm + ((lane >> 4) << 2);
  int ng0 = n0 + wn + (lane & 15);

  if constexpr (EPI == EPI_E){
    f16* Eb = Oh + (long)b * 65536;
#pragma unroll
    for (int mi = 0; mi < 4; mi++){
      float lmax[4] = {-1e30f, -1e30f, -1e30f, -1e30f};
#pragma unroll
      for (int ni = 0; ni < 4; ni++){
#pragma unroll
        for (int r = 0; r < 4; r++) lmax[r] = fmaxf(lmax[r], acc[mi][ni][r]);
      }
#pragma unroll
      for (int r = 0; r < 4; r++){
        float m_ = lmax[r];
        m_ = fmaxf(m_, __shfl_xor(m_, 1)); m_ = fmaxf(m_, __shfl_xor(m_, 2));
        m_ = fmaxf(m_, __shfl_xor(m_, 4)); m_ = fmaxf(m_, __shfl_xor(m_, 8));
        int mg = mg0 + mi * 16 + r;
        float s_ = 0.f;
#pragma unroll
        for (int ni = 0; ni < 4; ni++){
          float dd = acc[mi][ni][r] - m_;      // <= 0, small where it matters
          s_ += __expf(dd);
          Eb[mg * 256 + ng0 + ni * 16] = (f16)dd;
        }
        s_ += __shfl_xor(s_, 1); s_ += __shfl_xor(s_, 2);
        s_ += __shfl_xor(s_, 4); s_ += __shfl_xor(s_, 8);
        if ((lane & 15) == 0){
          long off = ((long)(b * 256 + mg)) * 4 + tx * 2 + (wid & 1);
          Pm[off] = m_; Pp[off] = s_;
        }
      }
    }
  } else if constexpr (EPI == EPI_QV){
    if (m0 < 256){
      f16* Ohb = Oh + (long)b * 65536;
#pragma unroll
      for (int mi = 0; mi < 4; mi++)
#pragma unroll
        for (int ni = 0; ni < 4; ni++){
          int mg = mg0 + mi * 16, ng = ng0 + ni * 16;
          f32x4 v = acc[mi][ni];
          f16x4 p;
#pragma unroll
          for (int r = 0; r < 4; r++) p[r] = (f16)v[r];
          *(f16x4*)(&Ohb[ng * 256 + mg]) = p;
        }
    } else {
      f16* Ohb = Oh2 + (long)b * 65536;
#pragma unroll
      for (int mi = 0; mi < 4; mi++)
#pragma unroll
        for (int ni = 0; ni < 4; ni++){
          int mg = mg0 + mi * 16 - 256, ng = ng0 + ni * 16;
          f32x4 v = acc[mi][ni];
#pragma unroll
          for (int r = 0; r < 4; r++) Ohb[(mg + r) * 256 + ng] = (f16)(v[r] + bias[mg + r]);
        }
    }
  } else if constexpr (EPI == EPI_PVDT){
    const f16* Ub = Uh + (long)b * 65536;
    f16* Ohb = Oh + (long)b * 65536;
#pragma unroll
    for (int mi = 0; mi < 4; mi++)
#pragma unroll
      for (int ni = 0; ni < 4; ni++){
        int mg = mg0 + mi * 16, ng = ng0 + ni * 16;
        f32x4 v = acc[mi][ni];
        f16x4 uv = *(const f16x4*)(&Ub[ng * 256 + mg]);
        f16x4 p;
#pragma unroll
        for (int r = 0; r < 4; r++) p[r] = (f16)((float)uv[r] - v[r]);
        *(f16x4*)(&Ohb[ng * 256 + mg]) = p;
      }
  } else { // EPI_Y16 / EPI_C16
    f16* Ohb = Oh + (long)b * 65536;
#pragma unroll
    for (int mi = 0; mi < 4; mi++){
      float sr[4] = {0.f, 0.f, 0.f, 0.f}, qr[4] = {0.f, 0.f, 0.f, 0.f};
#pragma unroll
      for (int ni = 0; ni < 4; ni++){
        int mg = mg0 + mi * 16, ng = ng0 + ni * 16;
        f32x4 v = acc[mi][ni];
#pragma unroll
        for (int r = 0; r < 4; r++){
          float vv = v[r];
          if constexpr (EPI == EPI_Y16) vv += bias[mg + r];
          f16 h = (f16)vv;
          float vf = (float)h;
          Ohb[(mg + r) * 256 + ng] = h;
          sr[r] += vf; qr[r] += vf * vf;
        }
      }
#pragma unroll
      for (int r = 0; r < 4; r++){
        float s = sr[r], q2 = qr[r];
        s += __shfl_xor(s, 1); q2 += __shfl_xor(q2, 1);
        s += __shfl_xor(s, 2); q2 += __shfl_xor(q2, 2);
        s += __shfl_xor(s, 4); q2 += __shfl_xor(q2, 4);
        s += __shfl_xor(s, 8); q2 += __shfl_xor(q2, 8);
        if ((lane & 15) == 0){
          int ch = wm + mi * 16 + (lane >> 4) * 4 + r;
          ssum[ch * 2 + (wid & 1)] = s;
          ssq [ch * 2 + (wid & 1)] = q2;
        }
      }
    }
    __syncthreads();
    if (t < 128){
      int c = m0 + t;
      float S = ssum[t * 2] + ssum[t * 2 + 1];
      float Q = ssq [t * 2] + ssq [t * 2 + 1];
      long off = (long)c * 512 + b * 2 + tx;
      Ps[off] = S; Pq[off] = Q;
    }
  }
}

// ---------------- finalize BN stats from per-block partials (round-11 verified) ----------------
__global__ __launch_bounds__(256) void bn_reduce_k(const float* __restrict__ Ps,
                                                   const float* __restrict__ Pq,
                                                   float* __restrict__ mean, float* __restrict__ rstd){
  int c = blockIdx.x, t = threadIdx.x;
  float s = Ps[c * 512 + t] + Ps[c * 512 + t + 256];
  float q = Pq[c * 512 + t] + Pq[c * 512 + t + 256];
  for (int off = 32; off > 0; off >>= 1){ s += __shfl_down(s, off); q += __shfl_down(q, off); }
  __shared__ float ss[4], qq[4];
  int lane = t & 63, w = t >> 6;
  if (lane == 0){ ss[w] = s; qq[w] = q; }
  __syncthreads();
  if (t == 0){
    float S = ss[0] + ss[1] + ss[2] + ss[3];
    float Q = qq[0] + qq[1] + qq[2] + qq[3];
    float m = S * (1.f / 65536.f);
    float var = Q * (1.f / 65536.f) - m * m;
    mean[c] = m;
    rstd[c] = rsqrtf(var + 1e-5f);
  }
}

// ---------------- fused smcomb + renorm; E holds Etilde (f16); XCD-pinned per batch ----------------
__global__ __launch_bounds__(256) void renorm2_k(const f16* __restrict__ E,
                                                 const float* __restrict__ Pm,
                                                 const float* __restrict__ Pp,
                                                 f16* __restrict__ AT){
  __shared__ float smx[256], srs[256];
  int t = threadIdx.x;
  // decode: 64 blocks per batch; batch b on XCD b%8
  int dd = blockIdx.x;
  int xcd = dd & 7, rem = dd >> 3;
  int sub = rem & 63, zhi = rem >> 6;
  int b = xcd + 8 * zhi;
  int rid0 = b * 256 + sub * 4;
  {
    long pbase = ((long)(b * 256 + t)) * 4;
    f32x4 pm = *(const f32x4*)(Pm + pbase);
    f32x4 pp = *(const f32x4*)(Pp + pbase);
    float mm = fmaxf(fmaxf(pm[0], pm[1]), fmaxf(pm[2], pm[3]));
    float s = pp[0] * __expf(pm[0] - mm) + pp[1] * __expf(pm[1] - mm)
            + pp[2] * __expf(pm[2] - mm) + pp[3] * __expf(pm[3] - mm);
    smx[t] = mm; srs[t] = 1.f / s;
  }
  __syncthreads();
  int rid = rid0 + (t >> 6);
  int m = rid & 255;
  int lane = t & 63;
  int q = lane >> 4;                       // columns lane*4..lane*4+3 all in quadrant q
  float pmrow = Pm[(long)(b * 256 + m) * 4 + q];
  f16x4 e4 = *(const f16x4*)(E + (long)b * 65536 + m * 256 + lane * 4);
  f32x4 mv = *(const f32x4*)(&smx[lane * 4]);
  f32x4 rv = *(const f32x4*)(&srs[lane * 4]);
  float tv[4];
  float cs = 0.f;
#pragma unroll
  for (int i = 0; i < 4; i++){
    tv[i] = __expf((float)e4[i] + pmrow - mv[i]) * rv[i];
    cs += tv[i];
  }
  for (int off = 32; off > 0; off >>= 1) cs += __shfl_xor(cs, off);
  float inv = 1.f / (1e-9f + cs);
  f16x4 o;
#pragma unroll
  for (int i = 0; i < 4; i++) o[i] = (f16)(tv[i] * inv);
  *(f16x4*)(AT + (long)rid * 256 + lane * 4) = o;
}

// ---------------- BN apply + relu (+2x residual), vectorized; XCD-pinned per batch ----------------
template<bool RESID, bool WN16, bool WT16, bool WDOUT>
__global__ __launch_bounds__(256) void bn_apply_k(
    const f16* __restrict__ Y, const f16* __restrict__ Uht,
    const float* __restrict__ mean, const float* __restrict__ rstd,
    const float* __restrict__ gamma, const float* __restrict__ beta,
    f16* __restrict__ on16, f16* __restrict__ ot16,
    float* __restrict__ odout)
{
  __shared__ float tile[64][65];
  __shared__ float tileU[64][65];
  // decode: 16 tiles per batch; batch b on XCD b%8
  int d = blockIdx.x + 4 * (blockIdx.y + 4 * blockIdx.z);
  int xcd = d & 7, rem = d >> 3;
  int q = rem & 15, zhi = rem >> 4;
  int b = xcd + 8 * zhi;
  int c0 = (q >> 2) * 64, n0 = (q & 3) * 64;
  int t = threadIdx.x, rr = t >> 3, ss = t & 7;
  long base = (long)b * 65536;
  if constexpr (RESID){
#pragma unroll
    for (int p = 0; p < 2; p++){
      int nl = rr + p * 32;
      f16x8 u = *(const f16x8*)(Uht + base + (n0 + nl) * 256 + c0 + ss * 8);
#pragma unroll
      for (int j = 0; j < 8; j++) tileU[ss * 8 + j][nl] = (float)u[j];
    }
    __syncthreads();
  }
#pragma unroll
  for (int p = 0; p < 2; p++){
    int cl = rr + p * 32;
    int c = c0 + cl;
    float mu = mean[c], rg = rstd[c] * gamma[c], be = beta[c];
    f16x8 y = *(const f16x8*)(Y + base + c * 256 + n0 + ss * 8);
    float v[8];
#pragma unroll
    for (int j = 0; j < 8; j++){
      float vv = fmaxf(((float)y[j] - mu) * rg + be, 0.f);
      if constexpr (RESID) vv += 2.f * tileU[cl][ss * 8 + j];
      v[j] = vv;
    }
    if constexpr (WN16){
      f16x8 h;
#pragma unroll
      for (int j = 0; j < 8; j++) h[j] = (f16)v[j];
      *(f16x8*)(on16 + base + c * 256 + n0 + ss * 8) = h;
    }
    if constexpr (WDOUT){
      f32x4 w0, w1;
#pragma unroll
      for (int j = 0; j < 4; j++){ w0[j] = v[j]; w1[j] = v[4 + j]; }
      float* od = odout + (long)b * 262144 + c * 256 + n0 + ss * 8;
      *(f32x4*)od = w0;
      *(f32x4*)(od + 4) = w1;
    }
    if constexpr (WT16){
#pragma unroll
      for (int j = 0; j < 8; j++) tile[cl][ss * 8 + j] = v[j];
    }
  }
  if constexpr (WT16){
    __syncthreads();
#pragma unroll
    for (int p = 0; p < 2; p++){
      int nl = rr + p * 32;
      f16x8 h;
#pragma unroll
      for (int j = 0; j < 8; j++) h[j] = (f16)tile[ss * 8 + j][nl];
      *(f16x8*)(ot16 + base + (n0 + nl) * 256 + c0 + ss * 8) = h;
    }
  }
}

extern "C" void kernel_launch(void* const* d_in, const int* in_sizes, int n_in,
                              void* d_out, int out_size, void* d_ws, size_t ws_size,
                              hipStream_t stream)
{
  (void)in_sizes; (void)n_in; (void)out_size; (void)ws_size;

  const float* x0  = (const float*)d_in[0];
  const float* cw  = (const float*)d_in[1];
  const float* bng = (const float*)d_in[2];
  const float* bnb = (const float*)d_in[3];
  const float* wqk = (const float*)d_in[4];
  const float* wv  = (const float*)d_in[5];
  const float* bv  = (const float*)d_in[6];
  const float* wt  = (const float*)d_in[7];
  const float* bt  = (const float*)d_in[8];
  const float* sag = (const float*)d_in[9];
  const float* sab = (const float*)d_in[10];

  const long T = 16777216; // elements per [B,C,N] tensor
  f16*  Ha  = (f16*)d_ws;          // operand ping
  f16*  Hb  = Ha + T;              // operand pong
  f16*  Yh  = Hb + T;              // pre-BN y (f16)
  f16*  XK  = Yh + T;              // xkT
  f16*  XV  = XK + T;              // xv
  f16*  ATb = XV + T;              // attnT fp16
  f16*  DT  = ATb + T;             // dT
  f16*  Eh  = DT + T;              // Etilde f16 [B][256][256]
  f16*  Wc  = Eh + T;
  f16*  Wqv = Wc + 6 * 65536;      // stacked [Wq;Wv] per layer, 512x256
  f16*  Wt_ = Wqv + 16 * 65536;
  float* mn = (float*)(Wt_ + 8 * 65536);
  float* rsd = mn + 256;
  float* Ps = rsd + 256;           // [256][512] BN partial sums
  float* Pq = Ps + 131072;
  float* Pm = Pq + 131072;         // [65536][4] softmax partial max (quadrant max)
  float* Pp = Pm + 262144;         // [65536][4] softmax partial sumexp

  f16* H[2] = {Ha, Hb};
  int cur = 0;

  dim3 thr(256);
  dim3 gg(2, 2, 256);
  dim3 gqv(2, 4, 256);
  dim3 tile(4, 4, 256);

  cast_all_k<<<dim3(512, 4), thr, 0, stream>>>(cw, wqk, wv, wt, Wc, Wqv, Wt_);
  transpose_f16_k<<<tile, thr, 0, stream>>>(x0, H[0]);

  // conv0: next operand = (relu(bn(W x)))^T
  gemm_f16<EPI_C16><<<gg, thr, 0, stream>>>(Wc, 0, H[cur], Yh, nullptr, nullptr, nullptr, Ps, Pq, nullptr, nullptr);
  bn_reduce_k<<<256, thr, 0, stream>>>(Ps, Pq, mn, rsd);
  bn_apply_k<false, false, true, false><<<tile, thr, 0, stream>>>(
      Yh, nullptr, mn, rsd, bng, bnb, nullptr, H[cur ^ 1], nullptr);
  cur ^= 1;
  // conv1
  gemm_f16<EPI_C16><<<gg, thr, 0, stream>>>(Wc + 65536, 0, H[cur], Yh, nullptr, nullptr, nullptr, Ps, Pq, nullptr, nullptr);
  bn_reduce_k<<<256, thr, 0, stream>>>(Ps, Pq, mn, rsd);
  bn_apply_k<false, false, true, false><<<tile, thr, 0, stream>>>(
      Yh, nullptr, mn, rsd, bng + 256, bnb + 256, nullptr, H[cur ^ 1], nullptr);
  cur ^= 1;

  for (int blk = 0; blk < 4; blk++){
    for (int s = 0; s < 2; s++){
      int li = 2 * blk + s;
      f16* Hc = H[cur];
      f16* Hn = H[cur ^ 1];
      // xkT (transposed) + xv (+bias) in one dispatch
      gemm_f16<EPI_QV><<<gqv, thr, 0, stream>>>(Wqv + (long)li * 131072, 0, Hc,
                                                XK, XV, bv + li * 256, nullptr, nullptr, nullptr, nullptr, nullptr);
      // Etilde = E - quadmax (f16) + softmax row partials
      gemm_f16<EPI_E><<<gg, thr, 0, stream>>>(XK, 65536, XK,
                                              Eh, nullptr, nullptr, nullptr, nullptr, nullptr, Pm, Pp);
      // fused smcomb + renorm (reconstructs exact exponent in f32)
      renorm2_k<<<dim3(16384), thr, 0, stream>>>(Eh, Pm, Pp, ATb);
      // dT = (u - xv attn')^T; u read from Hc (f16, contiguous)
      gemm_f16<EPI_PVDT><<<gg, thr, 0, stream>>>(XV, 65536, ATb,
                                                 DT, nullptr, nullptr, Hc, nullptr, nullptr, nullptr, nullptr);
      // y = wt d + bt -> Yh f16 (+ fused BN partials)
      gemm_f16<EPI_Y16><<<gg, thr, 0, stream>>>(Wt_ + (long)li * 65536, 0, DT,
                                                Yh, nullptr, bt + li * 256, nullptr, Ps, Pq, nullptr, nullptr);
      bn_reduce_k<<<256, thr, 0, stream>>>(Ps, Pq, mn, rsd);
      if (s == 0){
        // x1 = 2u + relu(bn(y)); Hn <- x1 normal (next operand)
        bn_apply_k<true, true, false, false><<<tile, thr, 0, stream>>>(
            Yh, Hc, mn, rsd, sag + li * 256, sab + li * 256, Hn, nullptr, nullptr);
      } else {
        // x11pre = 2u + relu(bn(y)); Hn <- transposed (next operand for block conv)
        bn_apply_k<true, false, true, false><<<tile, thr, 0, stream>>>(
            Yh, Hc, mn, rsd, sag + li * 256, sab + li * 256, nullptr, Hn, nullptr);
      }
      cur ^= 1;
    }
    // block conv + bn + relu -> d_out region blk + next operand (transposed)
    gemm_f16<EPI_C16><<<gg, thr, 0, stream>>>(Wc + (long)(blk + 2) * 65536, 0, H[cur],
                                              Yh, nullptr, nullptr, nullptr, Ps, Pq, nullptr, nullptr);
    bn_reduce_k<<<256, thr, 0, stream>>>(Ps, Pq, mn, rsd);
    bn_apply_k<false, false, true, true><<<tile, thr, 0, stream>>>(
        Yh, nullptr, mn, rsd, bng + (blk + 2) * 256, bnb + (blk + 2) * 256,
        nullptr, H[cur ^ 1], (float*)d_out + blk * 65536);
    cur ^= 1;
  }
}

// Round 16
// 1615.373 us; speedup vs baseline: 2.1021x; 1.0275x over previous
//
#include <hip/hip_runtime.h>
#include <hip/hip_bf16.h>

typedef _Float16 f16;
typedef __attribute__((ext_vector_type(8))) _Float16 f16x8;
typedef __attribute__((ext_vector_type(4))) _Float16 f16x4;
typedef __attribute__((ext_vector_type(4))) float f32x4;

#define GLOAD_LDS16(gp, lp) \
  __builtin_amdgcn_global_load_lds((const __attribute__((address_space(1))) void*)(gp), \
                                   (__attribute__((address_space(3))) void*)(lp), 16, 0, 0)

// ---------------- fused prologue: all weight casts + x0 transpose in ONE dispatch ----------------
// y in [0,4): weight casts (blocks with i >= n exit). y == 4: f32 [b][c][n] -> f16 [b][n][c].
__global__ __launch_bounds__(256) void prologue_k(const float* __restrict__ cw,
                                                  const float* __restrict__ wqk,
                                                  const float* __restrict__ wv,
                                                  const float* __restrict__ wt,
                                                  const float* __restrict__ x0,
                                                  f16* __restrict__ Wc, f16* __restrict__ Wqv,
                                                  f16* __restrict__ Wt_, f16* __restrict__ XT){
  __shared__ float tile[64][65];
  int y = blockIdx.y;
  int t = threadIdx.x;
  if (y == 4){
    int d = blockIdx.x;                 // [0,4096)
    int b = d >> 4, c0 = ((d >> 2) & 3) * 64, n0 = (d & 3) * 64;
    int nl = t & 63, cr = t >> 6;
    long base = (long)b * 65536;
#pragma unroll
    for (int i = 0; i < 16; i++){
      int cl = cr + 4 * i;
      tile[cl][nl] = x0[base + (c0 + cl) * 256 + (n0 + nl)];
    }
    __syncthreads();
    int cl2 = t & 63, nr2 = t >> 6;
#pragma unroll
    for (int i = 0; i < 16; i++){
      int nl2 = nr2 + 4 * i;
      XT[base + (n0 + nl2) * 256 + (c0 + cl2)] = (f16)tile[cl2][nl2];
    }
    return;
  }
  int i = (blockIdx.x * 256 + t) * 4;
  const float* in; f16* out; int n; long oidx;
  if (y == 0){ in = cw;  n = 6 * 65536; out = Wc;  oidx = i; }
  else if (y == 1){ in = wqk; n = 8 * 65536; out = Wqv; oidx = (long)(i >> 16) * 131072 + (i & 65535); }
  else if (y == 2){ in = wv;  n = 8 * 65536; out = Wqv; oidx = (long)(i >> 16) * 131072 + 65536 + (i & 65535); }
  else { in = wt;  n = 8 * 65536; out = Wt_; oidx = i; }
  if (i < n){
    f32x4 v = *(const f32x4*)(in + i);
    f16x4 o;
    o[0] = (f16)v[0]; o[1] = (f16)v[1]; o[2] = (f16)v[2]; o[3] = (f16)v[3];
    *(f16x4*)(out + oidx) = o;
  }
}

// ---------------- generic GEMM fp16 (gload_lds + XOR swizzle), round-7/10/14/15 verified ----------------
// XCD swizzle: batch b pinned to XCD b%8 (bijective decode of the linear dispatch index).
// EPI_E stores Etilde = E - quadmax (f16, batch stride 65536) + softmax row partials Pm/Pp.
#define EPI_E    0
#define EPI_QV   1
#define EPI_Y16  2
#define EPI_C16  3
#define EPI_PVDT 4

template<int EPI>
__global__ __launch_bounds__(256) void gemm_f16(
    const f16* __restrict__ A, long sA,
    const f16* __restrict__ Bt,
    f16* __restrict__ Oh, f16* __restrict__ Oh2,
    const float* __restrict__ bias,
    const f16* __restrict__ Uh,
    float* __restrict__ Ps, float* __restrict__ Pq,
    float* __restrict__ Pm, float* __restrict__ Pp)
{
  constexpr bool BNST = (EPI == EPI_Y16) || (EPI == EPI_C16);
  __shared__ f16 As[128][64];
  __shared__ f16 Bs[128][64];
  // --- XCD-aware decode: d%8 == b%8 for every tile of batch b ---
  int d = blockIdx.x + gridDim.x * (blockIdx.y + gridDim.y * blockIdx.z);
  int nq = gridDim.x * gridDim.y;          // tiles per batch (4 or 8)
  int xcd = d & 7, rem = d >> 3;
  int q = rem % nq, zhi = rem / nq;
  int b = xcd + 8 * zhi;
  int tx = q % gridDim.x, ty = q / gridDim.x;
  int m0 = ty * 128, n0 = tx * 128;
  const f16* Ab = A  + (long)b * sA;
  const f16* Bb = Bt + (long)b * 65536;
  int t = threadIdx.x;
  int lane = t & 63, wid = t >> 6;
  int wm = (wid >> 1) * 64, wn = (wid & 1) * 64;
  f32x4 acc[4][4] = {};

  int lr = lane >> 3;
  int kc = ((lane & 7) ^ lr) * 8;   // inverse-swizzled global column

  for (int kt = 0; kt < 4; kt++){
    int k0 = kt * 64;
    if (kt) __syncthreads();
#pragma unroll
    for (int i = 0; i < 4; i++){
      int chunk = wid * 4 + i;
      int r = chunk * 8 + lr;
      GLOAD_LDS16(Ab + (m0 + r) * 256 + k0 + kc, &As[chunk * 8][0]);
      GLOAD_LDS16(Bb + (n0 + r) * 256 + k0 + kc, &Bs[chunk * 8][0]);
    }
    __syncthreads();
#pragma unroll
    for (int ks = 0; ks < 2; ks++){
      f16x8 af[4], bfr[4];
      int ko = ks * 32 + (lane >> 4) * 8;
#pragma unroll
      for (int mi = 0; mi < 4; mi++){
        int rA = wm + mi * 16 + (lane & 15);
        af[mi] = *(const f16x8*)(&As[rA][ko ^ ((rA & 7) << 3)]);
      }
#pragma unroll
      for (int ni = 0; ni < 4; ni++){
        int rB = wn + ni * 16 + (lane & 15);
        bfr[ni] = *(const f16x8*)(&Bs[rB][ko ^ ((rB & 7) << 3)]);
      }
#pragma unroll
      for (int mi = 0; mi < 4; mi++)
#pragma unroll
        for (int ni = 0; ni < 4; ni++)
          acc[mi][ni] = __builtin_amdgcn_mfma_f32_16x16x32_f16(af[mi], bfr[ni], acc[mi][ni], 0, 0, 0);
    }
  }

  float* ssum = (float*)&As[0][0];
  float* ssq  = ssum + 256;
  if constexpr (BNST) __syncthreads();

  int mg0 = m0 + wm + ((lane >> 4) << 2);
  int ng0 = n0 + wn + (lane & 15);

  if constexpr (EPI == EPI_E){
    f16* Eb = Oh + (long)b * 65536;
#pragma unroll
    for (int mi = 0; mi < 4; mi++){
      float lmax[4] = {-1e30f, -1e30f, -1e30f, -1e30f};
#pragma unroll
      for (int ni = 0; ni < 4; ni++){
#pragma unroll
        for (int r = 0; r < 4; r++) lmax[r] = fmaxf(lmax[r], acc[mi][ni][r]);
      }
#pragma unroll
      for (int r = 0; r < 4; r++){
        float m_ = lmax[r];
        m_ = fmaxf(m_, __shfl_xor(m_, 1)); m_ = fmaxf(m_, __shfl_xor(m_, 2));
        m_ = fmaxf(m_, __shfl_xor(m_, 4)); m_ = fmaxf(m_, __shfl_xor(m_, 8));
        int mg = mg0 + mi * 16 + r;
        float s_ = 0.f;
#pragma unroll
        for (int ni = 0; ni < 4; ni++){
          float dd = acc[mi][ni][r] - m_;      // <= 0, small where it matters
          s_ += __expf(dd);
          Eb[mg * 256 + ng0 + ni * 16] = (f16)dd;
        }
        s_ += __shfl_xor(s_, 1); s_ += __shfl_xor(s_, 2);
        s_ += __shfl_xor(s_, 4); s_ += __shfl_xor(s_, 8);
        if ((lane & 15) == 0){
          long off = ((long)(b * 256 + mg)) * 4 + tx * 2 + (wid & 1);
          Pm[off] = m_; Pp[off] = s_;
        }
      }
    }
  } else if constexpr (EPI == EPI_QV){
    if (m0 < 256){
      f16* Ohb = Oh + (long)b * 65536;
#pragma unroll
      for (int mi = 0; mi < 4; mi++)
#pragma unroll
        for (int ni = 0; ni < 4; ni++){
          int mg = mg0 + mi * 16, ng = ng0 + ni * 16;
          f32x4 v = acc[mi][ni];
          f16x4 p;
#pragma unroll
          for (int r = 0; r < 4; r++) p[r] = (f16)v[r];
          *(f16x4*)(&Ohb[ng * 256 + mg]) = p;
        }
    } else {
      f16* Ohb = Oh2 + (long)b * 65536;
#pragma unroll
      for (int mi = 0; mi < 4; mi++)
#pragma unroll
        for (int ni = 0; ni < 4; ni++){
          int mg = mg0 + mi * 16 - 256, ng = ng0 + ni * 16;
          f32x4 v = acc[mi][ni];
#pragma unroll
          for (int r = 0; r < 4; r++) Ohb[(mg + r) * 256 + ng] = (f16)(v[r] + bias[mg + r]);
        }
    }
  } else if constexpr (EPI == EPI_PVDT){
    const f16* Ub = Uh + (long)b * 65536;
    f16* Ohb = Oh + (long)b * 65536;
#pragma unroll
    for (int mi = 0; mi < 4; mi++)
#pragma unroll
      for (int ni = 0; ni < 4; ni++){
        int mg = mg0 + mi * 16, ng = ng0 + ni * 16;
        f32x4 v = acc[mi][ni];
        f16x4 uv = *(const f16x4*)(&Ub[ng * 256 + mg]);
        f16x4 p;
#pragma unroll
        for (int r = 0; r < 4; r++) p[r] = (f16)((float)uv[r] - v[r]);
        *(f16x4*)(&Ohb[ng * 256 + mg]) = p;
      }
  } else { // EPI_Y16 / EPI_C16
    f16* Ohb = Oh + (long)b * 65536;
#pragma unroll
    for (int mi = 0; mi < 4; mi++){
      float sr[4] = {0.f, 0.f, 0.f, 0.f}, qr[4] = {0.f, 0.f, 0.f, 0.f};
#pragma unroll
      for (int ni = 0; ni < 4; ni++){
        int mg = mg0 + mi * 16, ng = ng0 + ni * 16;
        f32x4 v = acc[mi][ni];
#pragma unroll
        for (int r = 0; r < 4; r++){
          float vv = v[r];
          if constexpr (EPI == EPI_Y16) vv += bias[mg + r];
          f16 h = (f16)vv;
          float vf = (float)h;
          Ohb[(mg + r) * 256 + ng] = h;
          sr[r] += vf; qr[r] += vf * vf;
        }
      }
#pragma unroll
      for (int r = 0; r < 4; r++){
        float s = sr[r], q2 = qr[r];
        s += __shfl_xor(s, 1); q2 += __shfl_xor(q2, 1);
        s += __shfl_xor(s, 2); q2 += __shfl_xor(q2, 2);
        s += __shfl_xor(s, 4); q2 += __shfl_xor(q2, 4);
        s += __shfl_xor(s, 8); q2 += __shfl_xor(q2, 8);
        if ((lane & 15) == 0){
          int ch = wm + mi * 16 + (lane >> 4) * 4 + r;
          ssum[ch * 2 + (wid & 1)] = s;
          ssq [ch * 2 + (wid & 1)] = q2;
        }
      }
    }
    __syncthreads();
    if (t < 128){
      int c = m0 + t;
      float S = ssum[t * 2] + ssum[t * 2 + 1];
      float Q = ssq [t * 2] + ssq [t * 2 + 1];
      long off = (long)c * 512 + b * 2 + tx;
      Ps[off] = S; Pq[off] = Q;
    }
  }
}

// ---------------- finalize BN stats from per-block partials (round-11 verified) ----------------
__global__ __launch_bounds__(256) void bn_reduce_k(const float* __restrict__ Ps,
                                                   const float* __restrict__ Pq,
                                                   float* __restrict__ mean, float* __restrict__ rstd){
  int c = blockIdx.x, t = threadIdx.x;
  float s = Ps[c * 512 + t] + Ps[c * 512 + t + 256];
  float q = Pq[c * 512 + t] + Pq[c * 512 + t + 256];
  for (int off = 32; off > 0; off >>= 1){ s += __shfl_down(s, off); q += __shfl_down(q, off); }
  __shared__ float ss[4], qq[4];
  int lane = t & 63, w = t >> 6;
  if (lane == 0){ ss[w] = s; qq[w] = q; }
  __syncthreads();
  if (t == 0){
    float S = ss[0] + ss[1] + ss[2] + ss[3];
    float Q = qq[0] + qq[1] + qq[2] + qq[3];
    float m = S * (1.f / 65536.f);
    float var = Q * (1.f / 65536.f) - m * m;
    mean[c] = m;
    rstd[c] = rsqrtf(var + 1e-5f);
  }
}

// ---------------- fused smcomb + renorm; E holds Etilde (f16); XCD-pinned per batch ----------------
// FAT blocks: 2048 blocks x 32 rows -> Pm/Pp re-read 8x lower. Per-row math identical to round 15.
__global__ __launch_bounds__(256) void renorm2_k(const f16* __restrict__ E,
                                                 const float* __restrict__ Pm,
                                                 const float* __restrict__ Pp,
                                                 f16* __restrict__ AT){
  __shared__ float smx[256], srs[256];
  int t = threadIdx.x;
  // decode: 8 blocks per batch; batch b on XCD b%8
  int d = blockIdx.x;                 // [0,2048)
  int xcd = d & 7;
  int j = d >> 3;                     // [0,256)
  int zhi = j & 31;
  int sub = j >> 5;                   // [0,8): row-group within batch
  int b = xcd + 8 * zhi;
  {
    long pbase = ((long)(b * 256 + t)) * 4;
    f32x4 pm = *(const f32x4*)(Pm + pbase);
    f32x4 pp = *(const f32x4*)(Pp + pbase);
    float mm = fmaxf(fmaxf(pm[0], pm[1]), fmaxf(pm[2], pm[3]));
    float s = pp[0] * __expf(pm[0] - mm) + pp[1] * __expf(pm[1] - mm)
            + pp[2] * __expf(pm[2] - mm) + pp[3] * __expf(pm[3] - mm);
    smx[t] = mm; srs[t] = 1.f / s;
  }
  __syncthreads();
  int lane = t & 63;
  int w = t >> 6;
  int q = lane >> 4;                  // columns lane*4..lane*4+3 all in quadrant q
  f32x4 mv = *(const f32x4*)(&smx[lane * 4]);
  f32x4 rv = *(const f32x4*)(&srs[lane * 4]);
#pragma unroll
  for (int rp = 0; rp < 8; rp++){
    int m = sub * 32 + rp * 4 + w;
    long rid = (long)b * 256 + m;
    float pmrow = Pm[rid * 4 + q];
    f16x4 e4 = *(const f16x4*)(E + (long)b * 65536 + m * 256 + lane * 4);
    float tv[4];
    float cs = 0.f;
#pragma unroll
    for (int i = 0; i < 4; i++){
      tv[i] = __expf((float)e4[i] + pmrow - mv[i]) * rv[i];
      cs += tv[i];
    }
    for (int off = 32; off > 0; off >>= 1) cs += __shfl_xor(cs, off);
    float inv = 1.f / (1e-9f + cs);
    f16x4 o;
#pragma unroll
    for (int i = 0; i < 4; i++) o[i] = (f16)(tv[i] * inv);
    *(f16x4*)(AT + rid * 256 + lane * 4) = o;
  }
}

// ---------------- BN apply + relu (+2x residual), vectorized; XCD-pinned per batch ----------------
template<bool RESID, bool WN16, bool WT16, bool WDOUT>
__global__ __launch_bounds__(256) void bn_apply_k(
    const f16* __restrict__ Y, const f16* __restrict__ Uht,
    const float* __restrict__ mean, const float* __restrict__ rstd,
    const float* __restrict__ gamma, const float* __restrict__ beta,
    f16* __restrict__ on16, f16* __restrict__ ot16,
    float* __restrict__ odout)
{
  __shared__ float tile[64][65];
  __shared__ float tileU[64][65];
  // decode: 16 tiles per batch; batch b on XCD b%8
  int d = blockIdx.x + 4 * (blockIdx.y + 4 * blockIdx.z);
  int xcd = d & 7, rem = d >> 3;
  int q = rem & 15, zhi = rem >> 4;
  int b = xcd + 8 * zhi;
  int c0 = (q >> 2) * 64, n0 = (q & 3) * 64;
  int t = threadIdx.x, rr = t >> 3, ss = t & 7;
  long base = (long)b * 65536;
  if constexpr (RESID){
#pragma unroll
    for (int p = 0; p < 2; p++){
      int nl = rr + p * 32;
      f16x8 u = *(const f16x8*)(Uht + base + (n0 + nl) * 256 + c0 + ss * 8);
#pragma unroll
      for (int j = 0; j < 8; j++) tileU[ss * 8 + j][nl] = (float)u[j];
    }
    __syncthreads();
  }
#pragma unroll
  for (int p = 0; p < 2; p++){
    int cl = rr + p * 32;
    int c = c0 + cl;
    float mu = mean[c], rg = rstd[c] * gamma[c], be = beta[c];
    f16x8 y = *(const f16x8*)(Y + base + c * 256 + n0 + ss * 8);
    float v[8];
#pragma unroll
    for (int j = 0; j < 8; j++){
      float vv = fmaxf(((float)y[j] - mu) * rg + be, 0.f);
      if constexpr (RESID) vv += 2.f * tileU[cl][ss * 8 + j];
      v[j] = vv;
    }
    if constexpr (WN16){
      f16x8 h;
#pragma unroll
      for (int j = 0; j < 8; j++) h[j] = (f16)v[j];
      *(f16x8*)(on16 + base + c * 256 + n0 + ss * 8) = h;
    }
    if constexpr (WDOUT){
      f32x4 w0, w1;
#pragma unroll
      for (int j = 0; j < 4; j++){ w0[j] = v[j]; w1[j] = v[4 + j]; }
      float* od = odout + (long)b * 262144 + c * 256 + n0 + ss * 8;
      *(f32x4*)od = w0;
      *(f32x4*)(od + 4) = w1;
    }
    if constexpr (WT16){
#pragma unroll
      for (int j = 0; j < 8; j++) tile[cl][ss * 8 + j] = v[j];
    }
  }
  if constexpr (WT16){
    __syncthreads();
#pragma unroll
    for (int p = 0; p < 2; p++){
      int nl = rr + p * 32;
      f16x8 h;
#pragma unroll
      for (int j = 0; j < 8; j++) h[j] = (f16)tile[ss * 8 + j][nl];
      *(f16x8*)(ot16 + base + (n0 + nl) * 256 + c0 + ss * 8) = h;
    }
  }
}

extern "C" void kernel_launch(void* const* d_in, const int* in_sizes, int n_in,
                              void* d_out, int out_size, void* d_ws, size_t ws_size,
                              hipStream_t stream)
{
  (void)in_sizes; (void)n_in; (void)out_size; (void)ws_size;

  const float* x0  = (const float*)d_in[0];
  const float* cw  = (const float*)d_in[1];
  const float* bng = (const float*)d_in[2];
  const float* bnb = (const float*)d_in[3];
  const float* wqk = (const float*)d_in[4];
  const float* wv  = (const float*)d_in[5];
  const float* bv  = (const float*)d_in[6];
  const float* wt  = (const float*)d_in[7];
  const float* bt  = (const float*)d_in[8];
  const float* sag = (const float*)d_in[9];
  const float* sab = (const float*)d_in[10];

  const long T = 16777216; // elements per [B,C,N] tensor
  f16*  Ha  = (f16*)d_ws;          // operand ping
  f16*  Hb  = Ha + T;              // operand pong
  f16*  Yh  = Hb + T;              // pre-BN y (f16)
  f16*  XK  = Yh + T;              // xkT
  f16*  XV  = XK + T;              // xv
  f16*  ATb = XV + T;              // attnT fp16
  f16*  DT  = ATb + T;             // dT
  f16*  Eh  = DT + T;              // Etilde f16 [B][256][256]
  f16*  Wc  = Eh + T;
  f16*  Wqv = Wc + 6 * 65536;      // stacked [Wq;Wv] per layer, 512x256
  f16*  Wt_ = Wqv + 16 * 65536;
  float* mn = (float*)(Wt_ + 8 * 65536);
  float* rsd = mn + 256;
  float* Ps = rsd + 256;           // [256][512] BN partial sums
  float* Pq = Ps + 131072;
  float* Pm = Pq + 131072;         // [65536][4] softmax partial max (quadrant max)
  float* Pp = Pm + 262144;         // [65536][4] softmax partial sumexp

  f16* H[2] = {Ha, Hb};
  int cur = 0;

  dim3 thr(256);
  dim3 gg(2, 2, 256);
  dim3 gqv(2, 4, 256);
  dim3 tile(4, 4, 256);

  prologue_k<<<dim3(4096, 5), thr, 0, stream>>>(cw, wqk, wv, wt, x0, Wc, Wqv, Wt_, H[0]);

  // conv0: next operand = (relu(bn(W x)))^T
  gemm_f16<EPI_C16><<<gg, thr, 0, stream>>>(Wc, 0, H[cur], Yh, nullptr, nullptr, nullptr, Ps, Pq, nullptr, nullptr);
  bn_reduce_k<<<256, thr, 0, stream>>>(Ps, Pq, mn, rsd);
  bn_apply_k<false, false, true, false><<<tile, thr, 0, stream>>>(
      Yh, nullptr, mn, rsd, bng, bnb, nullptr, H[cur ^ 1], nullptr);
  cur ^= 1;
  // conv1
  gemm_f16<EPI_C16><<<gg, thr, 0, stream>>>(Wc + 65536, 0, H[cur], Yh, nullptr, nullptr, nullptr, Ps, Pq, nullptr, nullptr);
  bn_reduce_k<<<256, thr, 0, stream>>>(Ps, Pq, mn, rsd);
  bn_apply_k<false, false, true, false><<<tile, thr, 0, stream>>>(
      Yh, nullptr, mn, rsd, bng + 256, bnb + 256, nullptr, H[cur ^ 1], nullptr);
  cur ^= 1;

  for (int blk = 0; blk < 4; blk++){
    for (int s = 0; s < 2; s++){
      int li = 2 * blk + s;
      f16* Hc = H[cur];
      f16* Hn = H[cur ^ 1];
      // xkT (transposed) + xv (+bias) in one dispatch
      gemm_f16<EPI_QV><<<gqv, thr, 0, stream>>>(Wqv + (long)li * 131072, 0, Hc,
                                                XK, XV, bv + li * 256, nullptr, nullptr, nullptr, nullptr, nullptr);
      // Etilde = E - quadmax (f16) + softmax row partials
      gemm_f16<EPI_E><<<gg, thr, 0, stream>>>(XK, 65536, XK,
                                              Eh, nullptr, nullptr, nullptr, nullptr, nullptr, Pm, Pp);
      // fused smcomb + renorm (fat blocks, reconstructs exact exponent in f32)
      renorm2_k<<<dim3(2048), thr, 0, stream>>>(Eh, Pm, Pp, ATb);
      // dT = (u - xv attn')^T; u read from Hc (f16, contiguous)
      gemm_f16<EPI_PVDT><<<gg, thr, 0, stream>>>(XV, 65536, ATb,
                                                 DT, nullptr, nullptr, Hc, nullptr, nullptr, nullptr, nullptr);
      // y = wt d + bt -> Yh f16 (+ fused BN partials)
      gemm_f16<EPI_Y16><<<gg, thr, 0, stream>>>(Wt_ + (long)li * 65536, 0, DT,
                                                Yh, nullptr, bt + li * 256, nullptr, Ps, Pq, nullptr, nullptr);
      bn_reduce_k<<<256, thr, 0, stream>>>(Ps, Pq, mn, rsd);
      if (s == 0){
        // x1 = 2u + relu(bn(y)); Hn <- x1 normal (next operand)
        bn_apply_k<true, true, false, false><<<tile, thr, 0, stream>>>(
            Yh, Hc, mn, rsd, sag + li * 256, sab + li * 256, Hn, nullptr, nullptr);
      } else {
        // x11pre = 2u + relu(bn(y)); Hn <- transposed (next operand for block conv)
        bn_apply_k<true, false, true, false><<<tile, thr, 0, stream>>>(
            Yh, Hc, mn, rsd, sag + li * 256, sab + li * 256, nullptr, Hn, nullptr);
      }
      cur ^= 1;
    }
    // block conv + bn + relu -> d_out region blk + next operand (transposed)
    gemm_f16<EPI_C16><<<gg, thr, 0, stream>>>(Wc + (long)(blk + 2) * 65536, 0, H[cur],
                                              Yh, nullptr, nullptr, nullptr, Ps, Pq, nullptr, nullptr);
    bn_reduce_k<<<256, thr, 0, stream>>>(Ps, Pq, mn, rsd);
    bn_apply_k<false, false, true, true><<<tile, thr, 0, stream>>>(
        Yh, nullptr, mn, rsd, bng + (blk + 2) * 256, bnb + (blk + 2) * 256,
        nullptr, H[cur ^ 1], (float*)d_out + blk * 65536);
    cur ^= 1;
  }
}

// Round 17
// 1494.908 us; speedup vs baseline: 2.2715x; 1.0806x over previous
//
#include <hip/hip_runtime.h>
#include <hip/hip_bf16.h>

typedef _Float16 f16;
typedef __attribute__((ext_vector_type(8))) _Float16 f16x8;
typedef __attribute__((ext_vector_type(4))) _Float16 f16x4;
typedef __attribute__((ext_vector_type(4))) float f32x4;

#define GLOAD_LDS16(gp, lp) \
  __builtin_amdgcn_global_load_lds((const __attribute__((address_space(1))) void*)(gp), \
                                   (__attribute__((address_space(3))) void*)(lp), 16, 0, 0)

// ---------------- fused prologue: all weight casts + x0 transpose in ONE dispatch ----------------
__global__ __launch_bounds__(256) void prologue_k(const float* __restrict__ cw,
                                                  const float* __restrict__ wqk,
                                                  const float* __restrict__ wv,
                                                  const float* __restrict__ wt,
                                                  const float* __restrict__ x0,
                                                  f16* __restrict__ Wc, f16* __restrict__ Wqv,
                                                  f16* __restrict__ Wt_, f16* __restrict__ XT){
  __shared__ float tile[64][65];
  int y = blockIdx.y;
  int t = threadIdx.x;
  if (y == 4){
    int d = blockIdx.x;                 // [0,4096)
    int b = d >> 4, c0 = ((d >> 2) & 3) * 64, n0 = (d & 3) * 64;
    int nl = t & 63, cr = t >> 6;
    long base = (long)b * 65536;
#pragma unroll
    for (int i = 0; i < 16; i++){
      int cl = cr + 4 * i;
      tile[cl][nl] = x0[base + (c0 + cl) * 256 + (n0 + nl)];
    }
    __syncthreads();
    int cl2 = t & 63, nr2 = t >> 6;
#pragma unroll
    for (int i = 0; i < 16; i++){
      int nl2 = nr2 + 4 * i;
      XT[base + (n0 + nl2) * 256 + (c0 + cl2)] = (f16)tile[cl2][nl2];
    }
    return;
  }
  int i = (blockIdx.x * 256 + t) * 4;
  const float* in; f16* out; int n; long oidx;
  if (y == 0){ in = cw;  n = 6 * 65536; out = Wc;  oidx = i; }
  else if (y == 1){ in = wqk; n = 8 * 65536; out = Wqv; oidx = (long)(i >> 16) * 131072 + (i & 65535); }
  else if (y == 2){ in = wv;  n = 8 * 65536; out = Wqv; oidx = (long)(i >> 16) * 131072 + 65536 + (i & 65535); }
  else { in = wt;  n = 8 * 65536; out = Wt_; oidx = i; }
  if (i < n){
    f32x4 v = *(const f32x4*)(in + i);
    f16x4 o;
    o[0] = (f16)v[0]; o[1] = (f16)v[1]; o[2] = (f16)v[2]; o[3] = (f16)v[3];
    *(f16x4*)(out + oidx) = o;
  }
}

// ---------------- generic GEMM fp16 (gload_lds + XOR swizzle), verified lineage r7/10/14/15/16 ----------------
// XCD swizzle: batch b pinned to XCD b%8.
// EPI_QV: ty<2 -> xkT = Hc x Wq (operand-swapped, row-major store, bit-identical to old transpose);
//         ty>=2 -> xv = Wv x Hc + bias (row-major).
// EPI_PVDT: xrT = ATb x XV (operand-swapped); dT = Hc - xrT, all row-major.
// EPI_E stores Etilde = E - quadmax (f16) + softmax row partials Pm/Pp.
#define EPI_E    0
#define EPI_QV   1
#define EPI_Y16  2
#define EPI_C16  3
#define EPI_PVDT 4

template<int EPI>
__global__ __launch_bounds__(256) void gemm_f16(
    const f16* __restrict__ A, long sA,
    const f16* __restrict__ Bt,
    f16* __restrict__ Oh, f16* __restrict__ Oh2,
    const float* __restrict__ bias,
    const f16* __restrict__ Uh,
    float* __restrict__ Ps, float* __restrict__ Pq,
    float* __restrict__ Pm, float* __restrict__ Pp)
{
  constexpr bool BNST = (EPI == EPI_Y16) || (EPI == EPI_C16);
  __shared__ f16 As[128][64];
  __shared__ f16 Bs[128][64];
  // --- XCD-aware decode: d%8 == b%8 for every tile of batch b ---
  int d = blockIdx.x + gridDim.x * (blockIdx.y + gridDim.y * blockIdx.z);
  int nq = gridDim.x * gridDim.y;          // tiles per batch (4 or 8)
  int xcd = d & 7, rem = d >> 3;
  int q = rem % nq, zhi = rem / nq;
  int b = xcd + 8 * zhi;
  int tx = q % gridDim.x, ty = q / gridDim.x;
  int m0 = ty * 128, n0 = tx * 128;
  const f16* Ab;
  const f16* Bb;
  if constexpr (EPI == EPI_QV){
    m0 = (ty & 1) * 128;                   // local M within the half
    if ((ty >> 1) == 0){                   // XK half: A-rows = Hc positions, B-rows = Wq out-channels
      Ab = Bt + (long)b * 65536;
      Bb = A;
    } else {                               // XV half: A-rows = Wv out-channels, B-rows = Hc positions
      Ab = A + 65536;
      Bb = Bt + (long)b * 65536;
    }
  } else {
    Ab = A + (long)b * sA;
    Bb = Bt + (long)b * 65536;
  }
  int t = threadIdx.x;
  int lane = t & 63, wid = t >> 6;
  int wm = (wid >> 1) * 64, wn = (wid & 1) * 64;
  f32x4 acc[4][4] = {};

  int lr = lane >> 3;
  int kc = ((lane & 7) ^ lr) * 8;   // inverse-swizzled global column

  for (int kt = 0; kt < 4; kt++){
    int k0 = kt * 64;
    if (kt) __syncthreads();
#pragma unroll
    for (int i = 0; i < 4; i++){
      int chunk = wid * 4 + i;
      int r = chunk * 8 + lr;
      GLOAD_LDS16(Ab + (m0 + r) * 256 + k0 + kc, &As[chunk * 8][0]);
      GLOAD_LDS16(Bb + (n0 + r) * 256 + k0 + kc, &Bs[chunk * 8][0]);
    }
    __syncthreads();
#pragma unroll
    for (int ks = 0; ks < 2; ks++){
      f16x8 af[4], bfr[4];
      int ko = ks * 32 + (lane >> 4) * 8;
#pragma unroll
      for (int mi = 0; mi < 4; mi++){
        int rA = wm + mi * 16 + (lane & 15);
        af[mi] = *(const f16x8*)(&As[rA][ko ^ ((rA & 7) << 3)]);
      }
#pragma unroll
      for (int ni = 0; ni < 4; ni++){
        int rB = wn + ni * 16 + (lane & 15);
        bfr[ni] = *(const f16x8*)(&Bs[rB][ko ^ ((rB & 7) << 3)]);
      }
#pragma unroll
      for (int mi = 0; mi < 4; mi++)
#pragma unroll
        for (int ni = 0; ni < 4; ni++)
          acc[mi][ni] = __builtin_amdgcn_mfma_f32_16x16x32_f16(af[mi], bfr[ni], acc[mi][ni], 0, 0, 0);
    }
  }

  float* ssum = (float*)&As[0][0];
  float* ssq  = ssum + 256;
  if constexpr (BNST) __syncthreads();

  int mg0 = m0 + wm + ((lane >> 4) << 2);
  int ng0 = n0 + wn + (lane & 15);

  if constexpr (EPI == EPI_E){
    f16* Eb = Oh + (long)b * 65536;
#pragma unroll
    for (int mi = 0; mi < 4; mi++){
      float lmax[4] = {-1e30f, -1e30f, -1e30f, -1e30f};
#pragma unroll
      for (int ni = 0; ni < 4; ni++){
#pragma unroll
        for (int r = 0; r < 4; r++) lmax[r] = fmaxf(lmax[r], acc[mi][ni][r]);
      }
#pragma unroll
      for (int r = 0; r < 4; r++){
        float m_ = lmax[r];
        m_ = fmaxf(m_, __shfl_xor(m_, 1)); m_ = fmaxf(m_, __shfl_xor(m_, 2));
        m_ = fmaxf(m_, __shfl_xor(m_, 4)); m_ = fmaxf(m_, __shfl_xor(m_, 8));
        int mg = mg0 + mi * 16 + r;
        float s_ = 0.f;
#pragma unroll
        for (int ni = 0; ni < 4; ni++){
          float dd = acc[mi][ni][r] - m_;      // <= 0, small where it matters
          s_ += __expf(dd);
          Eb[mg * 256 + ng0 + ni * 16] = (f16)dd;
        }
        s_ += __shfl_xor(s_, 1); s_ += __shfl_xor(s_, 2);
        s_ += __shfl_xor(s_, 4); s_ += __shfl_xor(s_, 8);
        if ((lane & 15) == 0){
          long off = ((long)(b * 256 + mg)) * 4 + tx * 2 + (wid & 1);
          Pm[off] = m_; Pp[off] = s_;
        }
      }
    }
  } else if constexpr (EPI == EPI_QV){
    if ((ty >> 1) == 0){
      // XK: row-major store of xkT (bit-identical content to old transposed path)
      f16* Ohb = Oh + (long)b * 65536;
#pragma unroll
      for (int mi = 0; mi < 4; mi++)
#pragma unroll
        for (int ni = 0; ni < 4; ni++){
          int mg = mg0 + mi * 16, ng = ng0 + ni * 16;
          f32x4 v = acc[mi][ni];
#pragma unroll
          for (int r = 0; r < 4; r++) Ohb[(mg + r) * 256 + ng] = (f16)v[r];
        }
    } else {
      f16* Ohb = Oh2 + (long)b * 65536;
#pragma unroll
      for (int mi = 0; mi < 4; mi++)
#pragma unroll
        for (int ni = 0; ni < 4; ni++){
          int mg = mg0 + mi * 16, ng = ng0 + ni * 16;
          f32x4 v = acc[mi][ni];
#pragma unroll
          for (int r = 0; r < 4; r++) Ohb[(mg + r) * 256 + ng] = (f16)(v[r] + bias[mg + r]);
        }
    }
  } else if constexpr (EPI == EPI_PVDT){
    // dT[pos][c] = Hc[pos][c] - xrT[pos][c]; everything row-major
    const f16* Ub = Uh + (long)b * 65536;
    f16* Ohb = Oh + (long)b * 65536;
#pragma unroll
    for (int mi = 0; mi < 4; mi++)
#pragma unroll
      for (int ni = 0; ni < 4; ni++){
        int mg = mg0 + mi * 16, ng = ng0 + ni * 16;
        f32x4 v = acc[mi][ni];
#pragma unroll
        for (int r = 0; r < 4; r++)
          Ohb[(mg + r) * 256 + ng] = (f16)((float)Ub[(mg + r) * 256 + ng] - v[r]);
      }
  } else { // EPI_Y16 / EPI_C16
    f16* Ohb = Oh + (long)b * 65536;
#pragma unroll
    for (int mi = 0; mi < 4; mi++){
      float sr[4] = {0.f, 0.f, 0.f, 0.f}, qr[4] = {0.f, 0.f, 0.f, 0.f};
#pragma unroll
      for (int ni = 0; ni < 4; ni++){
        int mg = mg0 + mi * 16, ng = ng0 + ni * 16;
        f32x4 v = acc[mi][ni];
#pragma unroll
        for (int r = 0; r < 4; r++){
          float vv = v[r];
          if constexpr (EPI == EPI_Y16) vv += bias[mg + r];
          f16 h = (f16)vv;
          float vf = (float)h;
          Ohb[(mg + r) * 256 + ng] = h;
          sr[r] += vf; qr[r] += vf * vf;
        }
      }
#pragma unroll
      for (int r = 0; r < 4; r++){
        float s = sr[r], q2 = qr[r];
        s += __shfl_xor(s, 1); q2 += __shfl_xor(q2, 1);
        s += __shfl_xor(s, 2); q2 += __shfl_xor(q2, 2);
        s += __shfl_xor(s, 4); q2 += __shfl_xor(q2, 4);
        s += __shfl_xor(s, 8); q2 += __shfl_xor(q2, 8);
        if ((lane & 15) == 0){
          int ch = wm + mi * 16 + (lane >> 4) * 4 + r;
          ssum[ch * 2 + (wid & 1)] = s;
          ssq [ch * 2 + (wid & 1)] = q2;
        }
      }
    }
    __syncthreads();
    if (t < 128){
      int c = m0 + t;
      float S = ssum[t * 2] + ssum[t * 2 + 1];
      float Q = ssq [t * 2] + ssq [t * 2 + 1];
      long off = (long)c * 512 + b * 2 + tx;
      Ps[off] = S; Pq[off] = Q;
    }
  }
}

// ---------------- finalize BN stats from per-block partials (round-11 verified) ----------------
__global__ __launch_bounds__(256) void bn_reduce_k(const float* __restrict__ Ps,
                                                   const float* __restrict__ Pq,
                                                   float* __restrict__ mean, float* __restrict__ rstd){
  int c = blockIdx.x, t = threadIdx.x;
  float s = Ps[c * 512 + t] + Ps[c * 512 + t + 256];
  float q = Pq[c * 512 + t] + Pq[c * 512 + t + 256];
  for (int off = 32; off > 0; off >>= 1){ s += __shfl_down(s, off); q += __shfl_down(q, off); }
  __shared__ float ss[4], qq[4];
  int lane = t & 63, w = t >> 6;
  if (lane == 0){ ss[w] = s; qq[w] = q; }
  __syncthreads();
  if (t == 0){
    float S = ss[0] + ss[1] + ss[2] + ss[3];
    float Q = qq[0] + qq[1] + qq[2] + qq[3];
    float m = S * (1.f / 65536.f);
    float var = Q * (1.f / 65536.f) - m * m;
    mean[c] = m;
    rstd[c] = rsqrtf(var + 1e-5f);
  }
}

// ---------------- fused smcomb + renorm; E holds Etilde (f16); XCD-pinned, fat blocks ----------------
__global__ __launch_bounds__(256) void renorm2_k(const f16* __restrict__ E,
                                                 const float* __restrict__ Pm,
                                                 const float* __restrict__ Pp,
                                                 f16* __restrict__ AT){
  __shared__ float smx[256], srs[256];
  int t = threadIdx.x;
  int d = blockIdx.x;                 // [0,2048)
  int xcd = d & 7;
  int j = d >> 3;                     // [0,256)
  int zhi = j & 31;
  int sub = j >> 5;                   // [0,8): row-group within batch
  int b = xcd + 8 * zhi;
  {
    long pbase = ((long)(b * 256 + t)) * 4;
    f32x4 pm = *(const f32x4*)(Pm + pbase);
    f32x4 pp = *(const f32x4*)(Pp + pbase);
    float mm = fmaxf(fmaxf(pm[0], pm[1]), fmaxf(pm[2], pm[3]));
    float s = pp[0] * __expf(pm[0] - mm) + pp[1] * __expf(pm[1] - mm)
            + pp[2] * __expf(pm[2] - mm) + pp[3] * __expf(pm[3] - mm);
    smx[t] = mm; srs[t] = 1.f / s;
  }
  __syncthreads();
  int lane = t & 63;
  int w = t >> 6;
  int q = lane >> 4;                  // columns lane*4..lane*4+3 all in quadrant q
  f32x4 mv = *(const f32x4*)(&smx[lane * 4]);
  f32x4 rv = *(const f32x4*)(&srs[lane * 4]);
#pragma unroll
  for (int rp = 0; rp < 8; rp++){
    int m = sub * 32 + rp * 4 + w;
    long rid = (long)b * 256 + m;
    float pmrow = Pm[rid * 4 + q];
    f16x4 e4 = *(const f16x4*)(E + (long)b * 65536 + m * 256 + lane * 4);
    float tv[4];
    float cs = 0.f;
#pragma unroll
    for (int i = 0; i < 4; i++){
      tv[i] = __expf((float)e4[i] + pmrow - mv[i]) * rv[i];
      cs += tv[i];
    }
    for (int off = 32; off > 0; off >>= 1) cs += __shfl_xor(cs, off);
    float inv = 1.f / (1e-9f + cs);
    f16x4 o;
#pragma unroll
    for (int i = 0; i < 4; i++) o[i] = (f16)(tv[i] * inv);
    *(f16x4*)(AT + rid * 256 + lane * 4) = o;
  }
}

// ---------------- BN apply + relu (+2x residual), vectorized; XCD-pinned per batch ----------------
template<bool RESID, bool WN16, bool WT16, bool WDOUT>
__global__ __launch_bounds__(256) void bn_apply_k(
    const f16* __restrict__ Y, const f16* __restrict__ Uht,
    const float* __restrict__ mean, const float* __restrict__ rstd,
    const float* __restrict__ gamma, const float* __restrict__ beta,
    f16* __restrict__ on16, f16* __restrict__ ot16,
    float* __restrict__ odout)
{
  __shared__ float tile[64][65];
  __shared__ float tileU[64][65];
  int d = blockIdx.x + 4 * (blockIdx.y + 4 * blockIdx.z);
  int xcd = d & 7, rem = d >> 3;
  int q = rem & 15, zhi = rem >> 4;
  int b = xcd + 8 * zhi;
  int c0 = (q >> 2) * 64, n0 = (q & 3) * 64;
  int t = threadIdx.x, rr = t >> 3, ss = t & 7;
  long base = (long)b * 65536;
  if constexpr (RESID){
#pragma unroll
    for (int p = 0; p < 2; p++){
      int nl = rr + p * 32;
      f16x8 u = *(const f16x8*)(Uht + base + (n0 + nl) * 256 + c0 + ss * 8);
#pragma unroll
      for (int j = 0; j < 8; j++) tileU[ss * 8 + j][nl] = (float)u[j];
    }
    __syncthreads();
  }
#pragma unroll
  for (int p = 0; p < 2; p++){
    int cl = rr + p * 32;
    int c = c0 + cl;
    float mu = mean[c], rg = rstd[c] * gamma[c], be = beta[c];
    f16x8 y = *(const f16x8*)(Y + base + c * 256 + n0 + ss * 8);
    float v[8];
#pragma unroll
    for (int j = 0; j < 8; j++){
      float vv = fmaxf(((float)y[j] - mu) * rg + be, 0.f);
      if constexpr (RESID) vv += 2.f * tileU[cl][ss * 8 + j];
      v[j] = vv;
    }
    if constexpr (WN16){
      f16x8 h;
#pragma unroll
      for (int j = 0; j < 8; j++) h[j] = (f16)v[j];
      *(f16x8*)(on16 + base + c * 256 + n0 + ss * 8) = h;
    }
    if constexpr (WDOUT){
      f32x4 w0, w1;
#pragma unroll
      for (int j = 0; j < 4; j++){ w0[j] = v[j]; w1[j] = v[4 + j]; }
      float* od = odout + (long)b * 262144 + c * 256 + n0 + ss * 8;
      *(f32x4*)od = w0;
      *(f32x4*)(od + 4) = w1;
    }
    if constexpr (WT16){
#pragma unroll
      for (int j = 0; j < 8; j++) tile[cl][ss * 8 + j] = v[j];
    }
  }
  if constexpr (WT16){
    __syncthreads();
#pragma unroll
    for (int p = 0; p < 2; p++){
      int nl = rr + p * 32;
      f16x8 h;
#pragma unroll
      for (int j = 0; j < 8; j++) h[j] = (f16)tile[ss * 8 + j][nl];
      *(f16x8*)(ot16 + base + (n0 + nl) * 256 + c0 + ss * 8) = h;
    }
  }
}

extern "C" void kernel_launch(void* const* d_in, const int* in_sizes, int n_in,
                              void* d_out, int out_size, void* d_ws, size_t ws_size,
                              hipStream_t stream)
{
  (void)in_sizes; (void)n_in; (void)out_size; (void)ws_size;

  const float* x0  = (const float*)d_in[0];
  const float* cw  = (const float*)d_in[1];
  const float* bng = (const float*)d_in[2];
  const float* bnb = (const float*)d_in[3];
  const float* wqk = (const float*)d_in[4];
  const float* wv  = (const float*)d_in[5];
  const float* bv  = (const float*)d_in[6];
  const float* wt  = (const float*)d_in[7];
  const float* bt  = (const float*)d_in[8];
  const float* sag = (const float*)d_in[9];
  const float* sab = (const float*)d_in[10];

  const long T = 16777216; // elements per [B,C,N] tensor
  f16*  Ha  = (f16*)d_ws;          // operand ping
  f16*  Hb  = Ha + T;              // operand pong
  f16*  Yh  = Hb + T;              // pre-BN y (f16)
  f16*  XK  = Yh + T;              // xkT
  f16*  XV  = XK + T;              // xv
  f16*  ATb = XV + T;              // attnT fp16
  f16*  DT  = ATb + T;             // dT
  f16*  Eh  = DT + T;              // Etilde f16 [B][256][256]
  f16*  Wc  = Eh + T;
  f16*  Wqv = Wc + 6 * 65536;      // stacked [Wq;Wv] per layer, 512x256
  f16*  Wt_ = Wqv + 16 * 65536;
  float* mn = (float*)(Wt_ + 8 * 65536);
  float* rsd = mn + 256;
  float* Ps = rsd + 256;           // [256][512] BN partial sums
  float* Pq = Ps + 131072;
  float* Pm = Pq + 131072;         // [65536][4] softmax partial max (quadrant max)
  float* Pp = Pm + 262144;         // [65536][4] softmax partial sumexp

  f16* H[2] = {Ha, Hb};
  int cur = 0;

  dim3 thr(256);
  dim3 gg(2, 2, 256);
  dim3 gqv(2, 4, 256);
  dim3 tile(4, 4, 256);

  prologue_k<<<dim3(4096, 5), thr, 0, stream>>>(cw, wqk, wv, wt, x0, Wc, Wqv, Wt_, H[0]);

  // conv0: next operand = (relu(bn(W x)))^T
  gemm_f16<EPI_C16><<<gg, thr, 0, stream>>>(Wc, 0, H[cur], Yh, nullptr, nullptr, nullptr, Ps, Pq, nullptr, nullptr);
  bn_reduce_k<<<256, thr, 0, stream>>>(Ps, Pq, mn, rsd);
  bn_apply_k<false, false, true, false><<<tile, thr, 0, stream>>>(
      Yh, nullptr, mn, rsd, bng, bnb, nullptr, H[cur ^ 1], nullptr);
  cur ^= 1;
  // conv1
  gemm_f16<EPI_C16><<<gg, thr, 0, stream>>>(Wc + 65536, 0, H[cur], Yh, nullptr, nullptr, nullptr, Ps, Pq, nullptr, nullptr);
  bn_reduce_k<<<256, thr, 0, stream>>>(Ps, Pq, mn, rsd);
  bn_apply_k<false, false, true, false><<<tile, thr, 0, stream>>>(
      Yh, nullptr, mn, rsd, bng + 256, bnb + 256, nullptr, H[cur ^ 1], nullptr);
  cur ^= 1;

  for (int blk = 0; blk < 4; blk++){
    for (int s = 0; s < 2; s++){
      int li = 2 * blk + s;
      f16* Hc = H[cur];
      f16* Hn = H[cur ^ 1];
      // xkT (operand-swapped, row-major) + xv (+bias) in one dispatch
      gemm_f16<EPI_QV><<<gqv, thr, 0, stream>>>(Wqv + (long)li * 131072, 0, Hc,
                                                XK, XV, bv + li * 256, nullptr, nullptr, nullptr, nullptr, nullptr);
      // Etilde = E - quadmax (f16) + softmax row partials
      gemm_f16<EPI_E><<<gg, thr, 0, stream>>>(XK, 65536, XK,
                                              Eh, nullptr, nullptr, nullptr, nullptr, nullptr, Pm, Pp);
      // fused smcomb + renorm (fat blocks, exact exponent reconstruction)
      renorm2_k<<<dim3(2048), thr, 0, stream>>>(Eh, Pm, Pp, ATb);
      // dT = Hc - ATb x XV (operand-swapped: all row-major accesses)
      gemm_f16<EPI_PVDT><<<gg, thr, 0, stream>>>(ATb, 65536, XV,
                                                 DT, nullptr, nullptr, Hc, nullptr, nullptr, nullptr, nullptr);
      // y = wt d + bt -> Yh f16 (+ fused BN partials)
      gemm_f16<EPI_Y16><<<gg, thr, 0, stream>>>(Wt_ + (long)li * 65536, 0, DT,
                                                Yh, nullptr, bt + li * 256, nullptr, Ps, Pq, nullptr, nullptr);
      bn_reduce_k<<<256, thr, 0, stream>>>(Ps, Pq, mn, rsd);
      if (s == 0){
        // x1 = 2u + relu(bn(y)); Hn <- x1 normal (next operand)
        bn_apply_k<true, true, false, false><<<tile, thr, 0, stream>>>(
            Yh, Hc, mn, rsd, sag + li * 256, sab + li * 256, Hn, nullptr, nullptr);
      } else {
        // x11pre = 2u + relu(bn(y)); Hn <- transposed (next operand for block conv)
        bn_apply_k<true, false, true, false><<<tile, thr, 0, stream>>>(
            Yh, Hc, mn, rsd, sag + li * 256, sab + li * 256, nullptr, Hn, nullptr);
      }
      cur ^= 1;
    }
    // block conv + bn + relu -> d_out region blk + next operand (transposed)
    gemm_f16<EPI_C16><<<gg, thr, 0, stream>>>(Wc + (long)(blk + 2) * 65536, 0, H[cur],
                                              Yh, nullptr, nullptr, nullptr, Ps, Pq, nullptr, nullptr);
    bn_reduce_k<<<256, thr, 0, stream>>>(Ps, Pq, mn, rsd);
    bn_apply_k<false, false, true, true><<<tile, thr, 0, stream>>>(
        Yh, nullptr, mn, rsd, bng + (blk + 2) * 256, bnb + (blk + 2) * 256,
        nullptr, H[cur ^ 1], (float*)d_out + blk * 65536);
    cur ^= 1;
  }
}